// Round 2
// baseline (1939.425 us; speedup 1.0000x reference)
//
#include <hip/hip_runtime.h>
#include <hip/hip_cooperative_groups.h>
#include <math.h>

// SLIC superpixel segmentation — bit-faithful f32 reimplementation of the JAX ref
// (XLA CPU semantics). Numerics decisions, all aimed at exact label match:
//  - dot(feats, centers) replicates Eigen sgemm: sequential k=0..4 FMA chain.
//  - f_sq / c_sq: rounded squares, sequential adds, NO fma (fp contract off).
//  - d = (f_sq + c_sq) - 2*dot, three separately-rounded ops.
//  - argmin == first-min: (d < dmin) || (d == dmin && k < kbest) — order-free.
//  - segment_sum: EXACT ascending-pixel-index sequential adds per cluster.
// R21: the 22-dispatch loop was launch-boundary-bound (~70us of inter-kernel
// overhead; every per-kernel dur < 41us memset rows). Fused init + 10x(assign,
// update) + final assign into ONE persistent cooperative kernel (800 blocks x
// 256 thr, grid.sync between phases). LDS overlaid assign/update via union
// (21.3KB); __launch_bounds__(256,4) caps VGPR<=128 -> 4 blk/CU co-residency
// guaranteed. Persistent blocks also hoist per-tile pixel features (12 VGPRs)
// out of the iteration loop (computed once, was 11x). All arithmetic and
// orderings identical to the R18/R20 297us kernel -> bit-identical outputs.
// R22: fixed R21 compile error (macro used before definition — inlined it).
// Fallback to the multi-launch path if cooperative launch is refused.

#pragma clang fp contract(off)

namespace cg = cooperative_groups;

#define BATCH 8
#define HH 224
#define WW 224
#define HWPIX (HH * WW)        // 50176
#define KSEG 100
#define TPX 512                // pixels per tile
#define NTILE 98               // 512-px tiles per batch (98*512 == 50176)
#define NAT (BATCH * NTILE)    // 784 assign blocks
#define NBLK (BATCH * KSEG)    // 800 blocks (update work units)
#define NITER 10
#define UCH 1024               // update output chunk
#define UPITCH (UCH + 4)       // row stride: 4112B = 257*16, 16B-aligned

__device__ __forceinline__ float get_ratio() {
    double S = sqrt((double)(HH * WW) / (double)KSEG);
    return (float)(10.0 / S);
}

// ---- overlaid LDS: assign phase vs update phase never live simultaneously
struct SMUpdate {
    float ubuf[5][UPITCH];     // 20560B, rows 16B-aligned
    int srcL[NTILE];
    int dstL[NTILE + 1];
};
struct SMAssign {
    float sorted[5][TPX];      // 10240B
    float c8[KSEG * 8];        // [c0..c4, csq, pad, pad]
    int whist[8 * KSEG];       // group g = p*4 + w, lex order == pixel order
    int tilecnt[KSEG];
    int loffs[KSEG];
    float wmax[4];
    unsigned long long kmask[2];
    int sum0s;
};
union SMU {
    SMAssign a;
    SMUpdate u;
};

__global__ __launch_bounds__(256, 4) void k_fused(
    const float* __restrict__ img, float* __restrict__ centers,
    float* __restrict__ tileBuf, int* __restrict__ cntT,
    int* __restrict__ startT, float* __restrict__ outLab,
    float* __restrict__ outMean) {
#pragma clang fp contract(off)
    cg::grid_group grid = cg::this_grid();
    __shared__ alignas(16) SMU sm;

    const int blk = blockIdx.x;
    const int tid = threadIdx.x;
    const int lane = tid & 63, w = tid >> 6;
    const float ratio = get_ratio();

    // ---- init phase (replaces k_init): blocks 0..7, threads 0..99
    if (blk < BATCH && tid < KSEG) {
        int b = blk, k = tid;
        int i = k / 10, j = k % 10;
        int y = (int)floor(((i + 0.5) * (double)HH) / 10.0);
        int x = (int)floor(((j + 0.5) * (double)WW) / 10.0);
        int n = y * WW + x;
        const float* p = img + ((size_t)b * HWPIX + n) * 3;
        float* c = centers + (b * KSEG + k) * 5;
        c[0] = (float)y * ratio;
        c[1] = (float)x * ratio;
        c[2] = p[0];
        c[3] = p[1];
        c[4] = p[2];
    }

    const bool isA = (blk < NAT);
    const int b_a = blk / NTILE, tile = blk - b_a * NTILE;  // assign role
    const int b_u = blk / KSEG, k_u = blk - b_u * KSEG;     // update role
    const int n0 = tile * TPX + tid;

    // ---- persistent per-tile pixel features (computed ONCE, used 11x)
    float yf[2], xf[2], rr[2], gg[2], bb[2], fsq[2];
    int y0t = 0, y1t = 0, kA0 = 0, kA1 = 0;
    if (isA) {
#pragma unroll
        for (int p = 0; p < 2; ++p) {
            int n = n0 + p * 256;
            int y = n / WW, x = n - y * WW;
            yf[p] = (float)y * ratio;
            xf[p] = (float)x * ratio;
            const float* pp = img + ((size_t)b_a * HWPIX + n) * 3;
            rr[p] = pp[0]; gg[p] = pp[1]; bb[p] = pp[2];
            float s = yf[p] * yf[p];             // no fma, seq adds (XLA reduce)
            s = s + xf[p] * xf[p];
            s = s + rr[p] * rr[p];
            s = s + gg[p] * gg[p];
            s = s + bb[p] * bb[p];
            fsq[p] = s;
        }
        y0t = (tile * TPX) / WW;
        y1t = (tile * TPX + TPX - 1) / WW;
        int rmid = ((y0t + y1t) / 2) * 10 / HH;  // nearest init grid row
        int rlo = (rmid > 0) ? rmid - 1 : 0;
        int rhi = (rmid < 9) ? rmid + 1 : 9;
        kA0 = rlo * 10;
        kA1 = rhi * 10 + 10;
    }

    grid.sync();   // centers initialized

    for (int it = 0; it <= NITER; ++it) {
        // ================= assign phase (it<NITER: mode0; it==NITER: mode1)
        if (isA) {
            for (int i = tid; i < KSEG * 5; i += 256) {
                int k = i / 5, f = i - 5 * k;
                sm.a.c8[k * 8 + f] = centers[(size_t)b_a * KSEG * 5 + i];
            }
            if (it < NITER)
                for (int i = tid; i < 8 * KSEG; i += 256) sm.a.whist[i] = 0;
            __syncthreads();
            if (tid < KSEG) {
                const float* ck = sm.a.c8 + tid * 8;
                float s = ck[0] * ck[0];         // XLA fused mul+reduce: no fma
                s = s + ck[1] * ck[1];
                s = s + ck[2] * ck[2];
                s = s + ck[3] * ck[3];
                s = s + ck[4] * ck[4];
                sm.a.c8[tid * 8 + 5] = s;
            }
            __syncthreads();

            float dmin[2] = {INFINITY, INFINITY};
            int kb[2] = {0, 0};

#define EVALK(kk)                                                              \
    {                                                                          \
        int k_ = (kk);                                                         \
        float4 v0 = *reinterpret_cast<const float4*>(&sm.a.c8[k_ * 8]);        \
        float c4v = sm.a.c8[k_ * 8 + 4];                                       \
        float csqv = sm.a.c8[k_ * 8 + 5];                                      \
        _Pragma("unroll")                                                      \
        for (int p = 0; p < 2; ++p) {                                          \
            float dot = yf[p] * v0.x;                                          \
            dot = __fmaf_rn(xf[p], v0.y, dot);                                 \
            dot = __fmaf_rn(rr[p], v0.z, dot);                                 \
            dot = __fmaf_rn(gg[p], v0.w, dot);                                 \
            dot = __fmaf_rn(bb[p], c4v, dot);                                  \
            float d = (fsq[p] + csqv) - 2.0f * dot;                            \
            if (d < dmin[p] || (d == dmin[p] && k_ < kb[p])) {                 \
                dmin[p] = d; kb[p] = k_;                                       \
            }                                                                  \
        }                                                                      \
    }

            // ---- phase A: statically nearest cluster grid rows (ascending k)
            for (int k = kA0; k < kA1; ++k) EVALK(k);

            // ---- block-max dmin + rigorous margin
            float tmax = fmaxf(dmin[0], dmin[1]);
            for (int d = 32; d > 0; d >>= 1) tmax = fmaxf(tmax, __shfl_xor(tmax, d));
            if (lane == 0) sm.a.wmax[w] = tmax;
            __syncthreads();
            float dmaxB = fmaxf(fmaxf(sm.a.wmax[0], sm.a.wmax[1]),
                                fmaxf(sm.a.wmax[2], sm.a.wmax[3])) + 1.0f;

            // ---- keep-mask: remaining ks whose y lower bound could still win
            {
                bool keep = false;
                if (tid < KSEG) {
                    int k = tid;
                    bool instat = (k >= kA0 && k < kA1);
                    float cyf = sm.a.c8[k * 8 + 0];
                    float t0 = (float)y0t * ratio - cyf;
                    float t1 = cyf - (float)y1t * ratio;
                    float t = fmaxf(fmaxf(t0, t1), 0.0f);
                    keep = (!instat) && (t * t <= dmaxB);
                }
                unsigned long long bm = __ballot(keep);
                if (lane == 0 && w < 2) sm.a.kmask[w] = bm;
            }
            __syncthreads();

            // ---- phase B: surviving clusters (ascending k within each word)
            {
                unsigned long long m0 = sm.a.kmask[0], m1 = sm.a.kmask[1];
                while (m0) { int k = __builtin_ctzll(m0); m0 &= m0 - 1; EVALK(k); }
                while (m1) { int k = 64 + __builtin_ctzll(m1); m1 &= m1 - 1; EVALK(k); }
            }
#undef EVALK

            if (it == NITER) {
                // final outputs
#pragma unroll
                for (int p = 0; p < 2; ++p) {
                    int n = n0 + p * 256;
                    outLab[(size_t)b_a * HWPIX + n] = (float)kb[p];
                    float* om = outMean + ((size_t)b_a * HWPIX + n) * 3;
                    om[0] = sm.a.c8[kb[p] * 8 + 2];
                    om[1] = sm.a.c8[kb[p] * 8 + 3];
                    om[2] = sm.a.c8[kb[p] * 8 + 4];
                }
            } else {
                // ---- tile-local stable counting sort (order p, wave, lane == asc n)
                unsigned long long lmask_lt =
                    (lane == 0) ? 0ull : (~0ull >> (64 - lane));
                int rank_w[2], cnt_w[2];
#pragma unroll
                for (int p = 0; p < 2; ++p) {
                    unsigned long long todo = __ballot(1);
                    while (todo) {
                        int leader = __builtin_ctzll(todo);
                        int lval = __shfl(kb[p], leader);
                        unsigned long long mset = __ballot(kb[p] == lval);
                        if (kb[p] == lval) {
                            cnt_w[p] = (int)__popcll(mset);
                            rank_w[p] = (int)__popcll(mset & lmask_lt);
                        }
                        todo &= ~mset;
                    }
                }
#pragma unroll
                for (int p = 0; p < 2; ++p)
                    if (rank_w[p] == 0) sm.a.whist[(p * 4 + w) * KSEG + kb[p]] = cnt_w[p];
                __syncthreads();
                if (tid < KSEG) {
                    int s = 0;
#pragma unroll
                    for (int g = 0; g < 8; ++g) s += sm.a.whist[g * KSEG + tid];
                    sm.a.tilecnt[tid] = s;
                }
                __syncthreads();
                // exclusive scan of tilecnt[100]: two shfl-scan chunks + carry
                if (tid < 64) {
                    int v = sm.a.tilecnt[tid];
                    int incl = v;
                    for (int d = 1; d < 64; d <<= 1) {
                        int t = __shfl_up(incl, d);
                        if (lane >= d) incl += t;
                    }
                    sm.a.loffs[tid] = incl - v;
                    if (lane == 63) sm.a.sum0s = incl;
                }
                __syncthreads();
                if (w == 1) {                    // tid 64..127 -> k 64..99
                    int i2 = tid;
                    int v = (i2 < KSEG) ? sm.a.tilecnt[i2] : 0;
                    int incl = v;
                    for (int d = 1; d < 64; d <<= 1) {
                        int t = __shfl_up(incl, d);
                        if (lane >= d) incl += t;
                    }
                    if (i2 < KSEG) sm.a.loffs[i2] = sm.a.sum0s + incl - v;
                }
                __syncthreads();
                if (tid < KSEG) {
                    cntT[((size_t)b_a * KSEG + tid) * NTILE + tile] = sm.a.tilecnt[tid];
                    startT[((size_t)b_a * KSEG + tid) * NTILE + tile] = sm.a.loffs[tid];
                }

                // sort into LDS (scattered LDS writes, ~2-way aliasing ~= free)
#pragma unroll
                for (int p = 0; p < 2; ++p) {
                    int g = p * 4 + w;
                    int r = rank_w[p];
                    for (int g2 = 0; g2 < g; ++g2) r += sm.a.whist[g2 * KSEG + kb[p]];
                    int pos = sm.a.loffs[kb[p]] + r;
                    sm.a.sorted[0][pos] = yf[p];
                    sm.a.sorted[1][pos] = xf[p];
                    sm.a.sorted[2][pos] = rr[p];
                    sm.a.sorted[3][pos] = gg[p];
                    sm.a.sorted[4][pos] = bb[p];
                }
                __syncthreads();

                // ONE coalesced flat copy LDS -> tileBuf (2560 contiguous floats)
                float* tb = tileBuf + (size_t)(b_a * NTILE + tile) * 5 * TPX;
                const float* sflat = &sm.a.sorted[0][0];
                for (int i = tid; i < 5 * TPX; i += 256) tb[i] = sflat[i];
            }
        }

        if (it == NITER) break;   // final outputs written; done

        grid.sync();   // tileBuf/cntT/startT visible to update blocks

        // ================= update phase: one (b,k) per block, all 800 blocks
        {
            if (tid < 64) {
                int carry = 0;
                for (int c0 = 0; c0 < NTILE; c0 += 64) {
                    int idx = c0 + lane;
                    int c = (idx < NTILE) ? cntT[((size_t)b_u * KSEG + k_u) * NTILE + idx] : 0;
                    int s = (idx < NTILE) ? startT[((size_t)b_u * KSEG + k_u) * NTILE + idx] : 0;
                    int incl = c;
                    for (int d = 1; d < 64; d <<= 1) {   // Hillis-Steele inclusive
                        int t = __shfl_up(incl, d);
                        if (lane >= d) incl += t;
                    }
                    if (idx < NTILE) { sm.u.srcL[idx] = s; sm.u.dstL[idx] = carry + incl - c; }
                    carry += __shfl(incl, 63);
                }
                if (lane == 0) sm.u.dstL[NTILE] = carry;
            }
            __syncthreads();
            int total = sm.u.dstL[NTILE];

            float acc = 0.f;
            for (int c0 = 0; c0 < total; c0 += UCH) {
                int m = min(UCH, total - c0);
                for (int jj = tid; jj < m; jj += 256) {
                    int j = c0 + jj;
                    int lo = 0, hi = NTILE;      // dstL[0]=0 <= j < dstL[NTILE]
                    while (hi - lo > 1) {        // 7 steps
                        int mid = (lo + hi) >> 1;
                        if (sm.u.dstL[mid] <= j) lo = mid; else hi = mid;
                    }
                    int src = sm.u.srcL[lo] + (j - sm.u.dstL[lo]);
                    const float* tb = tileBuf + (size_t)(b_u * NTILE + lo) * 5 * TPX;
#pragma unroll
                    for (int ch = 0; ch < 5; ++ch)
                        sm.u.ubuf[ch][jj] = tb[ch * TPX + src];  // coalesced per channel
                }
                __syncthreads();
                if (tid < 5) {
                    float a = acc;
                    const float4* bp4 = reinterpret_cast<const float4*>(&sm.u.ubuf[tid][0]);
                    int nf4 = m >> 2;
#pragma unroll 4
                    for (int i = 0; i < nf4; ++i) {  // loads pipeline; adds ascending
                        float4 v = bp4[i];
                        a = a + v.x;
                        a = a + v.y;
                        a = a + v.z;
                        a = a + v.w;
                    }
                    for (int i = nf4 << 2; i < m; ++i) a = a + sm.u.ubuf[tid][i];
                    acc = a;
                }
                __syncthreads();
            }
            if (tid < 5 && total > 0) {          // where(counts>0, sums/counts, old)
                centers[(b_u * KSEG + k_u) * 5 + tid] = acc / (float)total;
            }
        }

        grid.sync();   // new centers visible to assign blocks
    }
}

// ======================= fallback path (original 22-launch pipeline) =========

__global__ void k_init(const float* __restrict__ img, float* __restrict__ centers) {
#pragma clang fp contract(off)
    int b = blockIdx.x;
    int k = threadIdx.x;
    if (k >= KSEG) return;
    int i = k / 10, j = k % 10;
    int y = (int)floor(((i + 0.5) * (double)HH) / 10.0);
    int x = (int)floor(((j + 0.5) * (double)WW) / 10.0);
    float ratio = get_ratio();
    int n = y * WW + x;
    const float* p = img + ((size_t)b * HWPIX + n) * 3;
    float* c = centers + (b * KSEG + k) * 5;
    c[0] = (float)y * ratio;
    c[1] = (float)x * ratio;
    c[2] = p[0];
    c[3] = p[1];
    c[4] = p[2];
}

__global__ void k_assign(const float* __restrict__ img, const float* __restrict__ centers,
                         float* __restrict__ tileBuf, int* __restrict__ cntT,
                         int* __restrict__ startT, float* __restrict__ outLab,
                         float* __restrict__ outMean, int mode) {
#pragma clang fp contract(off)
    __shared__ float c8[KSEG * 8];
    __shared__ int whist[8 * KSEG];
    __shared__ int tilecnt[KSEG];
    __shared__ int loffs[KSEG];
    __shared__ float sorted[5][TPX];
    __shared__ float wmax[4];
    __shared__ unsigned long long kmask[2];
    __shared__ int sum0s;
    int b = blockIdx.y, tile = blockIdx.x, tid = threadIdx.x;
    int lane = tid & 63, w = tid >> 6;

    for (int i = tid; i < KSEG * 5; i += 256) {
        int k = i / 5, f = i - 5 * k;
        c8[k * 8 + f] = centers[(size_t)b * KSEG * 5 + i];
    }
    if (mode == 0)
        for (int i = tid; i < 8 * KSEG; i += 256) whist[i] = 0;
    __syncthreads();
    if (tid < KSEG) {
        const float* ck = c8 + tid * 8;
        float s = ck[0] * ck[0];
        s = s + ck[1] * ck[1];
        s = s + ck[2] * ck[2];
        s = s + ck[3] * ck[3];
        s = s + ck[4] * ck[4];
        c8[tid * 8 + 5] = s;
    }
    __syncthreads();

    float ratio = get_ratio();
    int n0 = tile * TPX + tid;
    float yf[2], xf[2], rr[2], gg[2], bb[2], fsq[2], dmin[2];
    int kb[2];
#pragma unroll
    for (int p = 0; p < 2; ++p) {
        int n = n0 + p * 256;
        int y = n / WW, x = n - y * WW;
        yf[p] = (float)y * ratio;
        xf[p] = (float)x * ratio;
        const float* pp = img + ((size_t)b * HWPIX + n) * 3;
        rr[p] = pp[0]; gg[p] = pp[1]; bb[p] = pp[2];
        float s = yf[p] * yf[p];
        s = s + xf[p] * xf[p];
        s = s + rr[p] * rr[p];
        s = s + gg[p] * gg[p];
        s = s + bb[p] * bb[p];
        fsq[p] = s;
        dmin[p] = INFINITY;
        kb[p] = 0;
    }

#define EVALK(kk)                                                              \
    {                                                                          \
        int k_ = (kk);                                                         \
        float4 v0 = *reinterpret_cast<const float4*>(&c8[k_ * 8]);             \
        float c4v = c8[k_ * 8 + 4];                                            \
        float csqv = c8[k_ * 8 + 5];                                           \
        _Pragma("unroll")                                                      \
        for (int p = 0; p < 2; ++p) {                                          \
            float dot = yf[p] * v0.x;                                          \
            dot = __fmaf_rn(xf[p], v0.y, dot);                                 \
            dot = __fmaf_rn(rr[p], v0.z, dot);                                 \
            dot = __fmaf_rn(gg[p], v0.w, dot);                                 \
            dot = __fmaf_rn(bb[p], c4v, dot);                                  \
            float d = (fsq[p] + csqv) - 2.0f * dot;                            \
            if (d < dmin[p] || (d == dmin[p] && k_ < kb[p])) {                 \
                dmin[p] = d; kb[p] = k_;                                       \
            }                                                                  \
        }                                                                      \
    }

    int y0t = (tile * TPX) / WW, y1t = (tile * TPX + TPX - 1) / WW;
    int rmid = ((y0t + y1t) / 2) * 10 / HH;
    int rlo = (rmid > 0) ? rmid - 1 : 0;
    int rhi = (rmid < 9) ? rmid + 1 : 9;
    int kA0 = rlo * 10, kA1 = rhi * 10 + 10;
    for (int k = kA0; k < kA1; ++k) EVALK(k);

    float tmax = fmaxf(dmin[0], dmin[1]);
    for (int d = 32; d > 0; d >>= 1) tmax = fmaxf(tmax, __shfl_xor(tmax, d));
    if (lane == 0) wmax[w] = tmax;
    __syncthreads();
    float dmaxB = fmaxf(fmaxf(wmax[0], wmax[1]), fmaxf(wmax[2], wmax[3])) + 1.0f;

    {
        bool keep = false;
        if (tid < KSEG) {
            int k = tid;
            bool instat = (k >= kA0 && k < kA1);
            float cyf = c8[k * 8 + 0];
            float t0 = (float)y0t * ratio - cyf;
            float t1 = cyf - (float)y1t * ratio;
            float t = fmaxf(fmaxf(t0, t1), 0.0f);
            keep = (!instat) && (t * t <= dmaxB);
        }
        unsigned long long bm = __ballot(keep);
        if (lane == 0 && w < 2) kmask[w] = bm;
    }
    __syncthreads();

    {
        unsigned long long m0 = kmask[0], m1 = kmask[1];
        while (m0) { int k = __builtin_ctzll(m0); m0 &= m0 - 1; EVALK(k); }
        while (m1) { int k = 64 + __builtin_ctzll(m1); m1 &= m1 - 1; EVALK(k); }
    }
#undef EVALK

    if (mode == 1) {
#pragma unroll
        for (int p = 0; p < 2; ++p) {
            int n = n0 + p * 256;
            outLab[(size_t)b * HWPIX + n] = (float)kb[p];
            float* om = outMean + ((size_t)b * HWPIX + n) * 3;
            om[0] = c8[kb[p] * 8 + 2];
            om[1] = c8[kb[p] * 8 + 3];
            om[2] = c8[kb[p] * 8 + 4];
        }
        return;
    }

    unsigned long long lmask_lt = (lane == 0) ? 0ull : (~0ull >> (64 - lane));
    int rank_w[2], cnt_w[2];
#pragma unroll
    for (int p = 0; p < 2; ++p) {
        unsigned long long todo = __ballot(1);
        while (todo) {
            int leader = __builtin_ctzll(todo);
            int lval = __shfl(kb[p], leader);
            unsigned long long mset = __ballot(kb[p] == lval);
            if (kb[p] == lval) {
                cnt_w[p] = (int)__popcll(mset);
                rank_w[p] = (int)__popcll(mset & lmask_lt);
            }
            todo &= ~mset;
        }
    }
#pragma unroll
    for (int p = 0; p < 2; ++p)
        if (rank_w[p] == 0) whist[(p * 4 + w) * KSEG + kb[p]] = cnt_w[p];
    __syncthreads();
    if (tid < KSEG) {
        int s = 0;
#pragma unroll
        for (int g = 0; g < 8; ++g) s += whist[g * KSEG + tid];
        tilecnt[tid] = s;
    }
    __syncthreads();
    if (tid < 64) {
        int v = tilecnt[tid];
        int incl = v;
        for (int d = 1; d < 64; d <<= 1) {
            int t = __shfl_up(incl, d);
            if (lane >= d) incl += t;
        }
        loffs[tid] = incl - v;
        if (lane == 63) sum0s = incl;
    }
    __syncthreads();
    if (w == 1) {
        int i2 = tid;
        int v = (i2 < KSEG) ? tilecnt[i2] : 0;
        int incl = v;
        for (int d = 1; d < 64; d <<= 1) {
            int t = __shfl_up(incl, d);
            if (lane >= d) incl += t;
        }
        if (i2 < KSEG) loffs[i2] = sum0s + incl - v;
    }
    __syncthreads();
    if (tid < KSEG) {
        cntT[((size_t)b * KSEG + tid) * NTILE + tile] = tilecnt[tid];
        startT[((size_t)b * KSEG + tid) * NTILE + tile] = loffs[tid];
    }

#pragma unroll
    for (int p = 0; p < 2; ++p) {
        int g = p * 4 + w;
        int r = rank_w[p];
        for (int g2 = 0; g2 < g; ++g2) r += whist[g2 * KSEG + kb[p]];
        int pos = loffs[kb[p]] + r;
        sorted[0][pos] = yf[p];
        sorted[1][pos] = xf[p];
        sorted[2][pos] = rr[p];
        sorted[3][pos] = gg[p];
        sorted[4][pos] = bb[p];
    }
    __syncthreads();

    float* tb = tileBuf + (size_t)(b * NTILE + tile) * 5 * TPX;
    const float* sflat = &sorted[0][0];
    for (int i = tid; i < 5 * TPX; i += 256) tb[i] = sflat[i];
}

__global__ void k_update(const float* __restrict__ tileBuf, const int* __restrict__ cntT,
                         const int* __restrict__ startT, float* __restrict__ centers) {
#pragma clang fp contract(off)
    __shared__ int srcL[NTILE];
    __shared__ int dstL[NTILE + 1];
    __shared__ float ubuf[5][UPITCH];
    int k = blockIdx.x, b = blockIdx.y, tid = threadIdx.x;
    int lane = tid & 63;

    if (tid < 64) {
        int carry = 0;
        for (int c0 = 0; c0 < NTILE; c0 += 64) {
            int idx = c0 + lane;
            int c = (idx < NTILE) ? cntT[((size_t)b * KSEG + k) * NTILE + idx] : 0;
            int s = (idx < NTILE) ? startT[((size_t)b * KSEG + k) * NTILE + idx] : 0;
            int incl = c;
            for (int d = 1; d < 64; d <<= 1) {
                int t = __shfl_up(incl, d);
                if (lane >= d) incl += t;
            }
            if (idx < NTILE) { srcL[idx] = s; dstL[idx] = carry + incl - c; }
            carry += __shfl(incl, 63);
        }
        if (lane == 0) dstL[NTILE] = carry;
    }
    __syncthreads();
    int total = dstL[NTILE];

    float acc = 0.f;
    for (int c0 = 0; c0 < total; c0 += UCH) {
        int m = min(UCH, total - c0);
        for (int jj = tid; jj < m; jj += 256) {
            int j = c0 + jj;
            int lo = 0, hi = NTILE;
            while (hi - lo > 1) {
                int mid = (lo + hi) >> 1;
                if (dstL[mid] <= j) lo = mid; else hi = mid;
            }
            int src = srcL[lo] + (j - dstL[lo]);
            const float* tb = tileBuf + (size_t)(b * NTILE + lo) * 5 * TPX;
#pragma unroll
            for (int ch = 0; ch < 5; ++ch)
                ubuf[ch][jj] = tb[ch * TPX + src];
        }
        __syncthreads();
        if (tid < 5) {
            float a = acc;
            const float4* bp4 = reinterpret_cast<const float4*>(&ubuf[tid][0]);
            int nf4 = m >> 2;
#pragma unroll 4
            for (int i = 0; i < nf4; ++i) {
                float4 v = bp4[i];
                a = a + v.x;
                a = a + v.y;
                a = a + v.z;
                a = a + v.w;
            }
            for (int i = nf4 << 2; i < m; ++i) a = a + ubuf[tid][i];
            acc = a;
        }
        __syncthreads();
    }
    if (tid < 5 && total > 0) {
        centers[(b * KSEG + k) * 5 + tid] = acc / (float)total;
    }
}

extern "C" void kernel_launch(void* const* d_in, const int* in_sizes, int n_in,
                              void* d_out, int out_size, void* d_ws, size_t ws_size,
                              hipStream_t stream) {
    const float* img = (const float*)d_in[0];
    float* outLab = (float*)d_out;                         // [8,224,224] labels as f32
    float* outMean = outLab + (size_t)BATCH * HWPIX;       // [8,224,224,3]

    char* ws = (char*)d_ws;
    float* centers = (float*)ws;  ws += (size_t)BATCH * KSEG * 5 * sizeof(float);
    float* tileBuf = (float*)ws;  ws += (size_t)BATCH * NTILE * 5 * TPX * sizeof(float);
    int* cntT      = (int*)ws;    ws += (size_t)BATCH * KSEG * NTILE * sizeof(int);
    int* startT    = (int*)ws;    ws += (size_t)BATCH * KSEG * NTILE * sizeof(int);

    void* args[] = {(void*)&img, (void*)&centers, (void*)&tileBuf,
                    (void*)&cntT, (void*)&startT, (void*)&outLab, (void*)&outMean};
    hipError_t cerr = hipLaunchCooperativeKernel((const void*)k_fused, dim3(NBLK),
                                                 dim3(256), args, 0, stream);
    if (cerr != hipSuccess) {
        // fallback: original multi-launch pipeline (bit-identical outputs)
        k_init<<<dim3(BATCH), 128, 0, stream>>>(img, centers);
        for (int it = 0; it < NITER; ++it) {
            k_assign<<<dim3(NTILE, BATCH), 256, 0, stream>>>(img, centers, tileBuf, cntT,
                                                             startT, outLab, outMean, 0);
            k_update<<<dim3(KSEG, BATCH), 256, 0, stream>>>(tileBuf, cntT, startT, centers);
        }
        k_assign<<<dim3(NTILE, BATCH), 256, 0, stream>>>(img, centers, tileBuf, cntT,
                                                         startT, outLab, outMean, 1);
    }
}

// Round 3
// 511.748 us; speedup vs baseline: 3.7898x; 3.7898x over previous
//
#include <hip/hip_runtime.h>
#include <math.h>

// SLIC superpixel segmentation — bit-faithful f32 reimplementation of the JAX ref
// (XLA CPU semantics). Numerics decisions, all aimed at exact label match:
//  - dot(feats, centers) replicates Eigen sgemm: sequential k=0..4 FMA chain.
//  - f_sq / c_sq: rounded squares, sequential adds, NO fma (fp contract off).
//  - d = (f_sq + c_sq) - 2*dot, three separately-rounded ops.
//  - argmin == first-min: (d < dmin) || (d == dmin && k < kbest) — order-free.
//  - segment_sum: EXACT ascending-pixel-index sequential adds per cluster.
// R23: R22 measured cg::grid.sync() at ~84us/sync (1975us total, VALUBusy 3.9%
// — kernel 90% idle; agent-fence wbl2/inv over 8 non-coherent XCD L2s + CG's
// sleep backoff). Replaced with per-batch flag sync: ALL cross-barrier data
// (centers/tileBuf/cntT/startT) moves via relaxed agent-scope atomics (sc0 sc1
// -> coherence point, no L2 dirty lines, no wbl2/inv ever), release ordering =
// __syncthreads' vmcnt(0) drain + relaxed atomicAdd on flagA[b]/flagU[b],
// acquire = s_sleep spin on relaxed atomic load. Dependency graph acyclic in
// iteration -> deadlock-free; cooperative launch guarantees 800-block
// co-residency (proven by R22: occupancy 38.7%, VGPR 48). Init centers written
// by tile-0 blocks before their first flagA (covers total==0 keep-old case).
// Pixel features hoisted out of the iteration loop (computed once, was 11x).
// Same arithmetic/order as the 297us R20 multi-launch -> identical outputs.
// Fallback to the multi-launch path if cooperative launch is refused.

#pragma clang fp contract(off)

#define BATCH 8
#define HH 224
#define WW 224
#define HWPIX (HH * WW)        // 50176
#define KSEG 100
#define TPX 512                // pixels per tile
#define NTILE 98               // 512-px tiles per batch (98*512 == 50176)
#define NAT (BATCH * NTILE)    // 784 assign blocks
#define NBLK (BATCH * KSEG)    // 800 blocks (update work units)
#define NITER 10
#define UCH 1024               // update output chunk
#define UPITCH (UCH + 4)       // row stride: 4112B = 257*16, 16B-aligned
#define FLAGSTRIDE 32          // one flag per 128B line (contention isolation)

__device__ __forceinline__ float get_ratio() {
    double S = sqrt((double)(HH * WW) / (double)KSEG);
    return (float)(10.0 / S);
}

// ---- agent-scope (cross-XCD coherent, L0/L2-bypassing) accessors
__device__ __forceinline__ int aload_i(const int* p) {
    return __hip_atomic_load(p, __ATOMIC_RELAXED, __HIP_MEMORY_SCOPE_AGENT);
}
__device__ __forceinline__ float aload_f(const float* p) {
    return __hip_atomic_load(p, __ATOMIC_RELAXED, __HIP_MEMORY_SCOPE_AGENT);
}
__device__ __forceinline__ void astore_i(int* p, int v) {
    __hip_atomic_store(p, v, __ATOMIC_RELAXED, __HIP_MEMORY_SCOPE_AGENT);
}
__device__ __forceinline__ void astore_f(float* p, float v) {
    __hip_atomic_store(p, v, __ATOMIC_RELAXED, __HIP_MEMORY_SCOPE_AGENT);
}
__device__ __forceinline__ void wait_ge(int* p, int target) {
    while (__hip_atomic_load(p, __ATOMIC_RELAXED, __HIP_MEMORY_SCOPE_AGENT) < target)
        __builtin_amdgcn_s_sleep(1);
}
__device__ __forceinline__ void signal(int* p) {
    // caller has done __syncthreads() (drains vmcnt for ALL waves of the block,
    // so every sc1 store has reached the coherence point before this add)
    asm volatile("s_waitcnt vmcnt(0)" ::: "memory");
    __hip_atomic_fetch_add(p, 1, __ATOMIC_RELAXED, __HIP_MEMORY_SCOPE_AGENT);
}

// ---- overlaid LDS: assign phase vs update phase never live simultaneously
struct SMUpdate {
    float ubuf[5][UPITCH];     // 20560B, rows 16B-aligned
    int srcL[NTILE];
    int dstL[NTILE + 1];
};
struct SMAssign {
    float sorted[5][TPX];      // 10240B
    float c8[KSEG * 8];        // [c0..c4, csq, pad, pad]
    int whist[8 * KSEG];       // group g = p*4 + w, lex order == pixel order
    int tilecnt[KSEG];
    int loffs[KSEG];
    float wmax[4];
    unsigned long long kmask[2];
    int sum0s;
};
union SMU {
    SMAssign a;
    SMUpdate u;
};

__global__ __launch_bounds__(256, 4) void k_fused(
    const float* __restrict__ img, float* __restrict__ centers,
    float* __restrict__ tileBuf, int* __restrict__ cntT,
    int* __restrict__ startT, float* __restrict__ outLab,
    float* __restrict__ outMean, int* __restrict__ flags) {
#pragma clang fp contract(off)
    __shared__ alignas(16) SMU sm;

    const int blk = blockIdx.x;
    const int tid = threadIdx.x;
    const int lane = tid & 63, w = tid >> 6;
    const float ratio = get_ratio();

    const bool isA = (blk < NAT);
    const int b_a = blk / NTILE, tile = blk - b_a * NTILE;  // assign role
    const int b_u = blk / KSEG, k_u = blk - b_u * KSEG;     // update role
    const int n0 = tile * TPX + tid;
    int* flagA_a = flags + b_a * FLAGSTRIDE;        // assign-done counter (98/iter)
    int* flagU_a = flags + (BATCH + b_a) * FLAGSTRIDE;
    int* flagA_u = flags + b_u * FLAGSTRIDE;
    int* flagU_u = flags + (BATCH + b_u) * FLAGSTRIDE;  // update-done (100/iter)

    // ---- init centers to GLOBAL (tile-0 block per batch), covers total==0
    // keep-old-centers case. Visible to any reader via flagA happens-before.
    if (isA && tile == 0 && tid < KSEG) {
        int k = tid;
        int i = k / 10, j = k % 10;
        int y = (int)floor(((i + 0.5) * (double)HH) / 10.0);
        int x = (int)floor(((j + 0.5) * (double)WW) / 10.0);
        int n = y * WW + x;
        const float* p = img + ((size_t)b_a * HWPIX + n) * 3;
        float* c = centers + (b_a * KSEG + k) * 5;
        astore_f(&c[0], (float)y * ratio);
        astore_f(&c[1], (float)x * ratio);
        astore_f(&c[2], p[0]);
        astore_f(&c[3], p[1]);
        astore_f(&c[4], p[2]);
    }

    // ---- persistent per-tile pixel features (computed ONCE, used 11x)
    float yf[2], xf[2], rr[2], gg[2], bb[2], fsq[2];
    int y0t = 0, y1t = 0, kA0 = 0, kA1 = 0;
    if (isA) {
#pragma unroll
        for (int p = 0; p < 2; ++p) {
            int n = n0 + p * 256;
            int y = n / WW, x = n - y * WW;
            yf[p] = (float)y * ratio;
            xf[p] = (float)x * ratio;
            const float* pp = img + ((size_t)b_a * HWPIX + n) * 3;
            rr[p] = pp[0]; gg[p] = pp[1]; bb[p] = pp[2];
            float s = yf[p] * yf[p];             // no fma, seq adds (XLA reduce)
            s = s + xf[p] * xf[p];
            s = s + rr[p] * rr[p];
            s = s + gg[p] * gg[p];
            s = s + bb[p] * bb[p];
            fsq[p] = s;
        }
        y0t = (tile * TPX) / WW;
        y1t = (tile * TPX + TPX - 1) / WW;
        int rmid = ((y0t + y1t) / 2) * 10 / HH;  // nearest init grid row
        int rlo = (rmid > 0) ? rmid - 1 : 0;
        int rhi = (rmid < 9) ? rmid + 1 : 9;
        kA0 = rlo * 10;
        kA1 = rhi * 10 + 10;
    }

    for (int it = 0; it <= NITER; ++it) {
        // ================= assign phase (it<NITER: mode0; it==NITER: mode1)
        if (isA) {
            if (it == 0) {
                // local init centers: pure function of img (== k_init values)
                if (tid < KSEG) {
                    int k = tid;
                    int i = k / 10, j = k % 10;
                    int y = (int)floor(((i + 0.5) * (double)HH) / 10.0);
                    int x = (int)floor(((j + 0.5) * (double)WW) / 10.0);
                    int n = y * WW + x;
                    const float* p = img + ((size_t)b_a * HWPIX + n) * 3;
                    sm.a.c8[k * 8 + 0] = (float)y * ratio;
                    sm.a.c8[k * 8 + 1] = (float)x * ratio;
                    sm.a.c8[k * 8 + 2] = p[0];
                    sm.a.c8[k * 8 + 3] = p[1];
                    sm.a.c8[k * 8 + 4] = p[2];
                }
            } else {
                if (tid == 0) wait_ge(flagU_a, KSEG * it);   // updates it-1 done
                __syncthreads();
                for (int i = tid; i < KSEG * 5; i += 256) {
                    int k = i / 5, f = i - 5 * k;
                    sm.a.c8[k * 8 + f] =
                        aload_f(&centers[(size_t)b_a * KSEG * 5 + i]);
                }
            }
            if (it < NITER)
                for (int i = tid; i < 8 * KSEG; i += 256) sm.a.whist[i] = 0;
            __syncthreads();
            if (tid < KSEG) {
                const float* ck = sm.a.c8 + tid * 8;
                float s = ck[0] * ck[0];         // XLA fused mul+reduce: no fma
                s = s + ck[1] * ck[1];
                s = s + ck[2] * ck[2];
                s = s + ck[3] * ck[3];
                s = s + ck[4] * ck[4];
                sm.a.c8[tid * 8 + 5] = s;
            }
            __syncthreads();

            float dmin[2] = {INFINITY, INFINITY};
            int kb[2] = {0, 0};

#define EVALK(kk)                                                              \
    {                                                                          \
        int k_ = (kk);                                                         \
        float4 v0 = *reinterpret_cast<const float4*>(&sm.a.c8[k_ * 8]);        \
        float c4v = sm.a.c8[k_ * 8 + 4];                                       \
        float csqv = sm.a.c8[k_ * 8 + 5];                                      \
        _Pragma("unroll")                                                      \
        for (int p = 0; p < 2; ++p) {                                          \
            float dot = yf[p] * v0.x;                                          \
            dot = __fmaf_rn(xf[p], v0.y, dot);                                 \
            dot = __fmaf_rn(rr[p], v0.z, dot);                                 \
            dot = __fmaf_rn(gg[p], v0.w, dot);                                 \
            dot = __fmaf_rn(bb[p], c4v, dot);                                  \
            float d = (fsq[p] + csqv) - 2.0f * dot;                            \
            if (d < dmin[p] || (d == dmin[p] && k_ < kb[p])) {                 \
                dmin[p] = d; kb[p] = k_;                                       \
            }                                                                  \
        }                                                                      \
    }

            // ---- phase A: statically nearest cluster grid rows (ascending k)
            for (int k = kA0; k < kA1; ++k) EVALK(k);

            // ---- block-max dmin + rigorous margin
            float tmax = fmaxf(dmin[0], dmin[1]);
            for (int d = 32; d > 0; d >>= 1) tmax = fmaxf(tmax, __shfl_xor(tmax, d));
            if (lane == 0) sm.a.wmax[w] = tmax;
            __syncthreads();
            float dmaxB = fmaxf(fmaxf(sm.a.wmax[0], sm.a.wmax[1]),
                                fmaxf(sm.a.wmax[2], sm.a.wmax[3])) + 1.0f;

            // ---- keep-mask: remaining ks whose y lower bound could still win
            {
                bool keep = false;
                if (tid < KSEG) {
                    int k = tid;
                    bool instat = (k >= kA0 && k < kA1);
                    float cyf = sm.a.c8[k * 8 + 0];
                    float t0 = (float)y0t * ratio - cyf;
                    float t1 = cyf - (float)y1t * ratio;
                    float t = fmaxf(fmaxf(t0, t1), 0.0f);
                    keep = (!instat) && (t * t <= dmaxB);
                }
                unsigned long long bm = __ballot(keep);
                if (lane == 0 && w < 2) sm.a.kmask[w] = bm;
            }
            __syncthreads();

            // ---- phase B: surviving clusters (ascending k within each word)
            {
                unsigned long long m0 = sm.a.kmask[0], m1 = sm.a.kmask[1];
                while (m0) { int k = __builtin_ctzll(m0); m0 &= m0 - 1; EVALK(k); }
                while (m1) { int k = 64 + __builtin_ctzll(m1); m1 &= m1 - 1; EVALK(k); }
            }
#undef EVALK

            if (it == NITER) {
                // final outputs (host reads after kernel end — normal stores)
#pragma unroll
                for (int p = 0; p < 2; ++p) {
                    int n = n0 + p * 256;
                    outLab[(size_t)b_a * HWPIX + n] = (float)kb[p];
                    float* om = outMean + ((size_t)b_a * HWPIX + n) * 3;
                    om[0] = sm.a.c8[kb[p] * 8 + 2];
                    om[1] = sm.a.c8[kb[p] * 8 + 3];
                    om[2] = sm.a.c8[kb[p] * 8 + 4];
                }
            } else {
                // ---- tile-local stable counting sort (order p, wave, lane == asc n)
                unsigned long long lmask_lt =
                    (lane == 0) ? 0ull : (~0ull >> (64 - lane));
                int rank_w[2], cnt_w[2];
#pragma unroll
                for (int p = 0; p < 2; ++p) {
                    unsigned long long todo = __ballot(1);
                    while (todo) {
                        int leader = __builtin_ctzll(todo);
                        int lval = __shfl(kb[p], leader);
                        unsigned long long mset = __ballot(kb[p] == lval);
                        if (kb[p] == lval) {
                            cnt_w[p] = (int)__popcll(mset);
                            rank_w[p] = (int)__popcll(mset & lmask_lt);
                        }
                        todo &= ~mset;
                    }
                }
#pragma unroll
                for (int p = 0; p < 2; ++p)
                    if (rank_w[p] == 0) sm.a.whist[(p * 4 + w) * KSEG + kb[p]] = cnt_w[p];
                __syncthreads();
                if (tid < KSEG) {
                    int s = 0;
#pragma unroll
                    for (int g = 0; g < 8; ++g) s += sm.a.whist[g * KSEG + tid];
                    sm.a.tilecnt[tid] = s;
                }
                __syncthreads();
                // exclusive scan of tilecnt[100]: two shfl-scan chunks + carry
                if (tid < 64) {
                    int v = sm.a.tilecnt[tid];
                    int incl = v;
                    for (int d = 1; d < 64; d <<= 1) {
                        int t = __shfl_up(incl, d);
                        if (lane >= d) incl += t;
                    }
                    sm.a.loffs[tid] = incl - v;
                    if (lane == 63) sm.a.sum0s = incl;
                }
                __syncthreads();
                if (w == 1) {                    // tid 64..127 -> k 64..99
                    int i2 = tid;
                    int v = (i2 < KSEG) ? sm.a.tilecnt[i2] : 0;
                    int incl = v;
                    for (int d = 1; d < 64; d <<= 1) {
                        int t = __shfl_up(incl, d);
                        if (lane >= d) incl += t;
                    }
                    if (i2 < KSEG) sm.a.loffs[i2] = sm.a.sum0s + incl - v;
                }
                __syncthreads();
                if (tid < KSEG) {
                    astore_i(&cntT[((size_t)b_a * KSEG + tid) * NTILE + tile],
                             sm.a.tilecnt[tid]);
                    astore_i(&startT[((size_t)b_a * KSEG + tid) * NTILE + tile],
                             sm.a.loffs[tid]);
                }

                // sort into LDS (scattered LDS writes, ~2-way aliasing ~= free)
#pragma unroll
                for (int p = 0; p < 2; ++p) {
                    int g = p * 4 + w;
                    int r = rank_w[p];
                    for (int g2 = 0; g2 < g; ++g2) r += sm.a.whist[g2 * KSEG + kb[p]];
                    int pos = sm.a.loffs[kb[p]] + r;
                    sm.a.sorted[0][pos] = yf[p];
                    sm.a.sorted[1][pos] = xf[p];
                    sm.a.sorted[2][pos] = rr[p];
                    sm.a.sorted[3][pos] = gg[p];
                    sm.a.sorted[4][pos] = bb[p];
                }
                __syncthreads();

                // ONE coalesced flat copy LDS -> tileBuf (2560 contiguous floats)
                float* tb = tileBuf + (size_t)(b_a * NTILE + tile) * 5 * TPX;
                const float* sflat = &sm.a.sorted[0][0];
                for (int i = tid; i < 5 * TPX; i += 256)
                    astore_f(&tb[i], sflat[i]);

                __syncthreads();                 // drain all waves' sc1 stores
                if (tid == 0) signal(flagA_a);   // assign it done for this tile
            }
        }

        if (it == NITER) break;   // final outputs written; done

        // ================= update phase: one (b,k) per block, all 800 blocks
        {
            if (tid == 0) wait_ge(flagA_u, NTILE * (it + 1));  // all tiles done
            __syncthreads();
            if (tid < 64) {
                int carry = 0;
                for (int c0 = 0; c0 < NTILE; c0 += 64) {
                    int idx = c0 + lane;
                    int c = (idx < NTILE)
                        ? aload_i(&cntT[((size_t)b_u * KSEG + k_u) * NTILE + idx]) : 0;
                    int s = (idx < NTILE)
                        ? aload_i(&startT[((size_t)b_u * KSEG + k_u) * NTILE + idx]) : 0;
                    int incl = c;
                    for (int d = 1; d < 64; d <<= 1) {   // Hillis-Steele inclusive
                        int t = __shfl_up(incl, d);
                        if (lane >= d) incl += t;
                    }
                    if (idx < NTILE) { sm.u.srcL[idx] = s; sm.u.dstL[idx] = carry + incl - c; }
                    carry += __shfl(incl, 63);
                }
                if (lane == 0) sm.u.dstL[NTILE] = carry;
            }
            __syncthreads();
            int total = sm.u.dstL[NTILE];

            float acc = 0.f;
            for (int c0 = 0; c0 < total; c0 += UCH) {
                int m = min(UCH, total - c0);
                for (int jj = tid; jj < m; jj += 256) {
                    int j = c0 + jj;
                    int lo = 0, hi = NTILE;      // dstL[0]=0 <= j < dstL[NTILE]
                    while (hi - lo > 1) {        // 7 steps
                        int mid = (lo + hi) >> 1;
                        if (sm.u.dstL[mid] <= j) lo = mid; else hi = mid;
                    }
                    int src = sm.u.srcL[lo] + (j - sm.u.dstL[lo]);
                    const float* tb = tileBuf + (size_t)(b_u * NTILE + lo) * 5 * TPX;
#pragma unroll
                    for (int ch = 0; ch < 5; ++ch)
                        sm.u.ubuf[ch][jj] = aload_f(&tb[ch * TPX + src]);
                }
                __syncthreads();
                if (tid < 5) {
                    float a = acc;
                    const float4* bp4 = reinterpret_cast<const float4*>(&sm.u.ubuf[tid][0]);
                    int nf4 = m >> 2;
#pragma unroll 4
                    for (int i = 0; i < nf4; ++i) {  // loads pipeline; adds ascending
                        float4 v = bp4[i];
                        a = a + v.x;
                        a = a + v.y;
                        a = a + v.z;
                        a = a + v.w;
                    }
                    for (int i = nf4 << 2; i < m; ++i) a = a + sm.u.ubuf[tid][i];
                    acc = a;
                }
                __syncthreads();
            }
            if (tid < 5 && total > 0) {          // where(counts>0, sums/counts, old)
                astore_f(&centers[(b_u * KSEG + k_u) * 5 + tid], acc / (float)total);
            }
            __syncthreads();                     // drain stores AND tileBuf reads
            if (tid == 0) signal(flagU_u);       // update (b_u,k_u) done for it
        }
    }
}

// ======================= fallback path (original 22-launch pipeline) =========

__global__ void k_init(const float* __restrict__ img, float* __restrict__ centers) {
#pragma clang fp contract(off)
    int b = blockIdx.x;
    int k = threadIdx.x;
    if (k >= KSEG) return;
    int i = k / 10, j = k % 10;
    int y = (int)floor(((i + 0.5) * (double)HH) / 10.0);
    int x = (int)floor(((j + 0.5) * (double)WW) / 10.0);
    float ratio = get_ratio();
    int n = y * WW + x;
    const float* p = img + ((size_t)b * HWPIX + n) * 3;
    float* c = centers + (b * KSEG + k) * 5;
    c[0] = (float)y * ratio;
    c[1] = (float)x * ratio;
    c[2] = p[0];
    c[3] = p[1];
    c[4] = p[2];
}

__global__ void k_assign(const float* __restrict__ img, const float* __restrict__ centers,
                         float* __restrict__ tileBuf, int* __restrict__ cntT,
                         int* __restrict__ startT, float* __restrict__ outLab,
                         float* __restrict__ outMean, int mode) {
#pragma clang fp contract(off)
    __shared__ float c8[KSEG * 8];
    __shared__ int whist[8 * KSEG];
    __shared__ int tilecnt[KSEG];
    __shared__ int loffs[KSEG];
    __shared__ float sorted[5][TPX];
    __shared__ float wmax[4];
    __shared__ unsigned long long kmask[2];
    __shared__ int sum0s;
    int b = blockIdx.y, tile = blockIdx.x, tid = threadIdx.x;
    int lane = tid & 63, w = tid >> 6;

    for (int i = tid; i < KSEG * 5; i += 256) {
        int k = i / 5, f = i - 5 * k;
        c8[k * 8 + f] = centers[(size_t)b * KSEG * 5 + i];
    }
    if (mode == 0)
        for (int i = tid; i < 8 * KSEG; i += 256) whist[i] = 0;
    __syncthreads();
    if (tid < KSEG) {
        const float* ck = c8 + tid * 8;
        float s = ck[0] * ck[0];
        s = s + ck[1] * ck[1];
        s = s + ck[2] * ck[2];
        s = s + ck[3] * ck[3];
        s = s + ck[4] * ck[4];
        c8[tid * 8 + 5] = s;
    }
    __syncthreads();

    float ratio = get_ratio();
    int n0 = tile * TPX + tid;
    float yf[2], xf[2], rr[2], gg[2], bb[2], fsq[2], dmin[2];
    int kb[2];
#pragma unroll
    for (int p = 0; p < 2; ++p) {
        int n = n0 + p * 256;
        int y = n / WW, x = n - y * WW;
        yf[p] = (float)y * ratio;
        xf[p] = (float)x * ratio;
        const float* pp = img + ((size_t)b * HWPIX + n) * 3;
        rr[p] = pp[0]; gg[p] = pp[1]; bb[p] = pp[2];
        float s = yf[p] * yf[p];
        s = s + xf[p] * xf[p];
        s = s + rr[p] * rr[p];
        s = s + gg[p] * gg[p];
        s = s + bb[p] * bb[p];
        fsq[p] = s;
        dmin[p] = INFINITY;
        kb[p] = 0;
    }

#define EVALK(kk)                                                              \
    {                                                                          \
        int k_ = (kk);                                                         \
        float4 v0 = *reinterpret_cast<const float4*>(&c8[k_ * 8]);             \
        float c4v = c8[k_ * 8 + 4];                                            \
        float csqv = c8[k_ * 8 + 5];                                           \
        _Pragma("unroll")                                                      \
        for (int p = 0; p < 2; ++p) {                                          \
            float dot = yf[p] * v0.x;                                          \
            dot = __fmaf_rn(xf[p], v0.y, dot);                                 \
            dot = __fmaf_rn(rr[p], v0.z, dot);                                 \
            dot = __fmaf_rn(gg[p], v0.w, dot);                                 \
            dot = __fmaf_rn(bb[p], c4v, dot);                                  \
            float d = (fsq[p] + csqv) - 2.0f * dot;                            \
            if (d < dmin[p] || (d == dmin[p] && k_ < kb[p])) {                 \
                dmin[p] = d; kb[p] = k_;                                       \
            }                                                                  \
        }                                                                      \
    }

    int y0t = (tile * TPX) / WW, y1t = (tile * TPX + TPX - 1) / WW;
    int rmid = ((y0t + y1t) / 2) * 10 / HH;
    int rlo = (rmid > 0) ? rmid - 1 : 0;
    int rhi = (rmid < 9) ? rmid + 1 : 9;
    int kA0 = rlo * 10, kA1 = rhi * 10 + 10;
    for (int k = kA0; k < kA1; ++k) EVALK(k);

    float tmax = fmaxf(dmin[0], dmin[1]);
    for (int d = 32; d > 0; d >>= 1) tmax = fmaxf(tmax, __shfl_xor(tmax, d));
    if (lane == 0) wmax[w] = tmax;
    __syncthreads();
    float dmaxB = fmaxf(fmaxf(wmax[0], wmax[1]), fmaxf(wmax[2], wmax[3])) + 1.0f;

    {
        bool keep = false;
        if (tid < KSEG) {
            int k = tid;
            bool instat = (k >= kA0 && k < kA1);
            float cyf = c8[k * 8 + 0];
            float t0 = (float)y0t * ratio - cyf;
            float t1 = cyf - (float)y1t * ratio;
            float t = fmaxf(fmaxf(t0, t1), 0.0f);
            keep = (!instat) && (t * t <= dmaxB);
        }
        unsigned long long bm = __ballot(keep);
        if (lane == 0 && w < 2) kmask[w] = bm;
    }
    __syncthreads();

    {
        unsigned long long m0 = kmask[0], m1 = kmask[1];
        while (m0) { int k = __builtin_ctzll(m0); m0 &= m0 - 1; EVALK(k); }
        while (m1) { int k = 64 + __builtin_ctzll(m1); m1 &= m1 - 1; EVALK(k); }
    }
#undef EVALK

    if (mode == 1) {
#pragma unroll
        for (int p = 0; p < 2; ++p) {
            int n = n0 + p * 256;
            outLab[(size_t)b * HWPIX + n] = (float)kb[p];
            float* om = outMean + ((size_t)b * HWPIX + n) * 3;
            om[0] = c8[kb[p] * 8 + 2];
            om[1] = c8[kb[p] * 8 + 3];
            om[2] = c8[kb[p] * 8 + 4];
        }
        return;
    }

    unsigned long long lmask_lt = (lane == 0) ? 0ull : (~0ull >> (64 - lane));
    int rank_w[2], cnt_w[2];
#pragma unroll
    for (int p = 0; p < 2; ++p) {
        unsigned long long todo = __ballot(1);
        while (todo) {
            int leader = __builtin_ctzll(todo);
            int lval = __shfl(kb[p], leader);
            unsigned long long mset = __ballot(kb[p] == lval);
            if (kb[p] == lval) {
                cnt_w[p] = (int)__popcll(mset);
                rank_w[p] = (int)__popcll(mset & lmask_lt);
            }
            todo &= ~mset;
        }
    }
#pragma unroll
    for (int p = 0; p < 2; ++p)
        if (rank_w[p] == 0) whist[(p * 4 + w) * KSEG + kb[p]] = cnt_w[p];
    __syncthreads();
    if (tid < KSEG) {
        int s = 0;
#pragma unroll
        for (int g = 0; g < 8; ++g) s += whist[g * KSEG + tid];
        tilecnt[tid] = s;
    }
    __syncthreads();
    if (tid < 64) {
        int v = tilecnt[tid];
        int incl = v;
        for (int d = 1; d < 64; d <<= 1) {
            int t = __shfl_up(incl, d);
            if (lane >= d) incl += t;
        }
        loffs[tid] = incl - v;
        if (lane == 63) sum0s = incl;
    }
    __syncthreads();
    if (w == 1) {
        int i2 = tid;
        int v = (i2 < KSEG) ? tilecnt[i2] : 0;
        int incl = v;
        for (int d = 1; d < 64; d <<= 1) {
            int t = __shfl_up(incl, d);
            if (lane >= d) incl += t;
        }
        if (i2 < KSEG) loffs[i2] = sum0s + incl - v;
    }
    __syncthreads();
    if (tid < KSEG) {
        cntT[((size_t)b * KSEG + tid) * NTILE + tile] = tilecnt[tid];
        startT[((size_t)b * KSEG + tid) * NTILE + tile] = loffs[tid];
    }

#pragma unroll
    for (int p = 0; p < 2; ++p) {
        int g = p * 4 + w;
        int r = rank_w[p];
        for (int g2 = 0; g2 < g; ++g2) r += whist[g2 * KSEG + kb[p]];
        int pos = loffs[kb[p]] + r;
        sorted[0][pos] = yf[p];
        sorted[1][pos] = xf[p];
        sorted[2][pos] = rr[p];
        sorted[3][pos] = gg[p];
        sorted[4][pos] = bb[p];
    }
    __syncthreads();

    float* tb = tileBuf + (size_t)(b * NTILE + tile) * 5 * TPX;
    const float* sflat = &sorted[0][0];
    for (int i = tid; i < 5 * TPX; i += 256) tb[i] = sflat[i];
}

__global__ void k_update(const float* __restrict__ tileBuf, const int* __restrict__ cntT,
                         const int* __restrict__ startT, float* __restrict__ centers) {
#pragma clang fp contract(off)
    __shared__ int srcL[NTILE];
    __shared__ int dstL[NTILE + 1];
    __shared__ float ubuf[5][UPITCH];
    int k = blockIdx.x, b = blockIdx.y, tid = threadIdx.x;
    int lane = tid & 63;

    if (tid < 64) {
        int carry = 0;
        for (int c0 = 0; c0 < NTILE; c0 += 64) {
            int idx = c0 + lane;
            int c = (idx < NTILE) ? cntT[((size_t)b * KSEG + k) * NTILE + idx] : 0;
            int s = (idx < NTILE) ? startT[((size_t)b * KSEG + k) * NTILE + idx] : 0;
            int incl = c;
            for (int d = 1; d < 64; d <<= 1) {
                int t = __shfl_up(incl, d);
                if (lane >= d) incl += t;
            }
            if (idx < NTILE) { srcL[idx] = s; dstL[idx] = carry + incl - c; }
            carry += __shfl(incl, 63);
        }
        if (lane == 0) dstL[NTILE] = carry;
    }
    __syncthreads();
    int total = dstL[NTILE];

    float acc = 0.f;
    for (int c0 = 0; c0 < total; c0 += UCH) {
        int m = min(UCH, total - c0);
        for (int jj = tid; jj < m; jj += 256) {
            int j = c0 + jj;
            int lo = 0, hi = NTILE;
            while (hi - lo > 1) {
                int mid = (lo + hi) >> 1;
                if (dstL[mid] <= j) lo = mid; else hi = mid;
            }
            int src = srcL[lo] + (j - dstL[lo]);
            const float* tb = tileBuf + (size_t)(b * NTILE + lo) * 5 * TPX;
#pragma unroll
            for (int ch = 0; ch < 5; ++ch)
                ubuf[ch][jj] = tb[ch * TPX + src];
        }
        __syncthreads();
        if (tid < 5) {
            float a = acc;
            const float4* bp4 = reinterpret_cast<const float4*>(&ubuf[tid][0]);
            int nf4 = m >> 2;
#pragma unroll 4
            for (int i = 0; i < nf4; ++i) {
                float4 v = bp4[i];
                a = a + v.x;
                a = a + v.y;
                a = a + v.z;
                a = a + v.w;
            }
            for (int i = nf4 << 2; i < m; ++i) a = a + ubuf[tid][i];
            acc = a;
        }
        __syncthreads();
    }
    if (tid < 5 && total > 0) {
        centers[(b * KSEG + k) * 5 + tid] = acc / (float)total;
    }
}

extern "C" void kernel_launch(void* const* d_in, const int* in_sizes, int n_in,
                              void* d_out, int out_size, void* d_ws, size_t ws_size,
                              hipStream_t stream) {
    const float* img = (const float*)d_in[0];
    float* outLab = (float*)d_out;                         // [8,224,224] labels as f32
    float* outMean = outLab + (size_t)BATCH * HWPIX;       // [8,224,224,3]

    char* ws = (char*)d_ws;
    float* centers = (float*)ws;  ws += (size_t)BATCH * KSEG * 5 * sizeof(float);
    float* tileBuf = (float*)ws;  ws += (size_t)BATCH * NTILE * 5 * TPX * sizeof(float);
    int* cntT      = (int*)ws;    ws += (size_t)BATCH * KSEG * NTILE * sizeof(int);
    int* startT    = (int*)ws;    ws += (size_t)BATCH * KSEG * NTILE * sizeof(int);
    int* flags     = (int*)ws;    ws += (size_t)2 * BATCH * FLAGSTRIDE * sizeof(int);

    // zero the sync flags (captured as a memset node; re-runs on every replay)
    hipMemsetAsync(flags, 0, (size_t)2 * BATCH * FLAGSTRIDE * sizeof(int), stream);

    void* args[] = {(void*)&img, (void*)&centers, (void*)&tileBuf,
                    (void*)&cntT, (void*)&startT, (void*)&outLab,
                    (void*)&outMean, (void*)&flags};
    hipError_t cerr = hipLaunchCooperativeKernel((const void*)k_fused, dim3(NBLK),
                                                 dim3(256), args, 0, stream);
    if (cerr != hipSuccess) {
        // fallback: original multi-launch pipeline (bit-identical outputs)
        k_init<<<dim3(BATCH), 128, 0, stream>>>(img, centers);
        for (int it = 0; it < NITER; ++it) {
            k_assign<<<dim3(NTILE, BATCH), 256, 0, stream>>>(img, centers, tileBuf, cntT,
                                                             startT, outLab, outMean, 0);
            k_update<<<dim3(KSEG, BATCH), 256, 0, stream>>>(tileBuf, cntT, startT, centers);
        }
        k_assign<<<dim3(NTILE, BATCH), 256, 0, stream>>>(img, centers, tileBuf, cntT,
                                                         startT, outLab, outMean, 1);
    }
}

// Round 4
// 266.620 us; speedup vs baseline: 7.2741x; 1.9194x over previous
//
#include <hip/hip_runtime.h>
#include <math.h>

// SLIC superpixel segmentation — bit-faithful f32 reimplementation of the JAX ref
// (XLA CPU semantics). Numerics decisions, all aimed at exact label match:
//  - dot(feats, centers) replicates Eigen sgemm: sequential k=0..4 FMA chain.
//  - f_sq / c_sq: rounded squares, sequential adds, NO fma (fp contract off).
//  - d = (f_sq + c_sq) - 2*dot, three separately-rounded ops.
//  - argmin == first-min: (d < dmin) || (d == dmin && k < kbest) — order-free.
//  - segment_sum: EXACT ascending-pixel-index sequential adds per cluster.
// R24: back to the PROVEN 22-launch structure (R20, 297us). Budget re-derive:
// 297 = 41us ws-fill + ~30us of 22 graph-replay boundaries (~1.3us each — NOT
// 3.5; fused R22/R23 persistent kernels lost because in-kernel cross-XCD sync
// (grid.sync 84us; MALL-flag ~11us incl. poll contention) can't beat 1.3us
// boundaries, and sc0sc1 L2-bypass taxed every tileBuf access. Addressable
// term = the ~227us of work: tileBuf carried 5 floats/px only to give update
// exact-order features, but features are a pure function of pixel index ->
// assign now writes the sorted pixel-INDEX list (1 int/px, 5x less traffic,
// 1 LDS scatter not 5, assign LDS 21.5->9.3KB); update re-derives y,x via
// exact int div + identical "(float)y*ratio" expression and loads r,g,b from
// read-only img (kernel-boundary coherence, no atomics). Same serial-chain
// order -> bit-identical outputs.

#pragma clang fp contract(off)

#define BATCH 8
#define HH 224
#define WW 224
#define HWPIX (HH * WW)        // 50176
#define KSEG 100
#define TPX 512                // pixels per tile
#define NTILE 98               // 512-px tiles per batch (98*512 == 50176)
#define NITER 10
#define UCH 1024               // update output chunk
#define UPITCH (UCH + 4)       // row stride: 4112B = 257*16, 16B-aligned

__device__ __forceinline__ float get_ratio() {
    double S = sqrt((double)(HH * WW) / (double)KSEG);
    return (float)(10.0 / S);
}

__global__ void k_init(const float* __restrict__ img, float* __restrict__ centers) {
#pragma clang fp contract(off)
    int b = blockIdx.x;
    int k = threadIdx.x;
    if (k >= KSEG) return;
    int i = k / 10, j = k % 10;
    int y = (int)floor(((i + 0.5) * (double)HH) / 10.0);
    int x = (int)floor(((j + 0.5) * (double)WW) / 10.0);
    float ratio = get_ratio();
    int n = y * WW + x;
    const float* p = img + ((size_t)b * HWPIX + n) * 3;
    float* c = centers + (b * KSEG + k) * 5;
    c[0] = (float)y * ratio;
    c[1] = (float)x * ratio;
    c[2] = p[0];
    c[3] = p[1];
    c[4] = p[2];
}

// 2 pixels/thread: n = tile*512 + p*256 + tid. Ascending n == lex (p, w, lane).
// mode 0: argmin (pruned) + tile-local counting sort -> tileIdx (sorted pixel
//         indices) + cnt/start.
// mode 1: final outputs only.
__global__ void k_assign(const float* __restrict__ img, const float* __restrict__ centers,
                         int* __restrict__ tileIdx, int* __restrict__ cntT,
                         int* __restrict__ startT, float* __restrict__ outLab,
                         float* __restrict__ outMean, int mode) {
#pragma clang fp contract(off)
    __shared__ float c8[KSEG * 8];   // [c0..c4, csq, pad, pad]
    __shared__ int whist[8 * KSEG];  // group g = p*4 + w, lex order == pixel order
    __shared__ int tilecnt[KSEG];
    __shared__ int loffs[KSEG];
    __shared__ int sortedIdx[TPX];   // sorted pixel indices (replaces 5-ch floats)
    __shared__ float wmax[4];
    __shared__ unsigned long long kmask[2];
    __shared__ int sum0s;
    int b = blockIdx.y, tile = blockIdx.x, tid = threadIdx.x;
    int lane = tid & 63, w = tid >> 6;

    for (int i = tid; i < KSEG * 5; i += 256) {
        int k = i / 5, f = i - 5 * k;
        c8[k * 8 + f] = centers[(size_t)b * KSEG * 5 + i];
    }
    if (mode == 0)
        for (int i = tid; i < 8 * KSEG; i += 256) whist[i] = 0;
    __syncthreads();
    if (tid < KSEG) {
        const float* ck = c8 + tid * 8;
        float s = ck[0] * ck[0];             // XLA fused mul+reduce: no fma, seq adds
        s = s + ck[1] * ck[1];
        s = s + ck[2] * ck[2];
        s = s + ck[3] * ck[3];
        s = s + ck[4] * ck[4];
        c8[tid * 8 + 5] = s;
    }
    __syncthreads();

    float ratio = get_ratio();
    int n0 = tile * TPX + tid;
    float yf[2], xf[2], rr[2], gg[2], bb[2], fsq[2], dmin[2];
    int kb[2];
#pragma unroll
    for (int p = 0; p < 2; ++p) {
        int n = n0 + p * 256;
        int y = n / WW, x = n - y * WW;
        yf[p] = (float)y * ratio;
        xf[p] = (float)x * ratio;
        const float* pp = img + ((size_t)b * HWPIX + n) * 3;
        rr[p] = pp[0]; gg[p] = pp[1]; bb[p] = pp[2];
        float s = yf[p] * yf[p];             // no fma, seq adds (XLA reduce)
        s = s + xf[p] * xf[p];
        s = s + rr[p] * rr[p];
        s = s + gg[p] * gg[p];
        s = s + bb[p] * bb[p];
        fsq[p] = s;
        dmin[p] = INFINITY;
        kb[p] = 0;
    }

    // evaluate one cluster exactly (reference op order); order-free first-min rule
#define EVALK(kk)                                                              \
    {                                                                          \
        int k_ = (kk);                                                         \
        float4 v0 = *reinterpret_cast<const float4*>(&c8[k_ * 8]);             \
        float c4v = c8[k_ * 8 + 4];                                            \
        float csqv = c8[k_ * 8 + 5];                                           \
        _Pragma("unroll")                                                      \
        for (int p = 0; p < 2; ++p) {                                          \
            float dot = yf[p] * v0.x;                                          \
            dot = __fmaf_rn(xf[p], v0.y, dot);                                 \
            dot = __fmaf_rn(rr[p], v0.z, dot);                                 \
            dot = __fmaf_rn(gg[p], v0.w, dot);                                 \
            dot = __fmaf_rn(bb[p], c4v, dot);                                  \
            float d = (fsq[p] + csqv) - 2.0f * dot;                            \
            if (d < dmin[p] || (d == dmin[p] && k_ < kb[p])) {                 \
                dmin[p] = d; kb[p] = k_;                                       \
            }                                                                  \
        }                                                                      \
    }

    // ---- phase A: statically nearest cluster grid rows (ascending k)
    int y0t = (tile * TPX) / WW, y1t = (tile * TPX + TPX - 1) / WW;
    int rmid = ((y0t + y1t) / 2) * 10 / HH;          // nearest init grid row
    int rlo = (rmid > 0) ? rmid - 1 : 0;
    int rhi = (rmid < 9) ? rmid + 1 : 9;
    int kA0 = rlo * 10, kA1 = rhi * 10 + 10;         // 20..30 clusters
    for (int k = kA0; k < kA1; ++k) EVALK(k);

    // ---- block-max dmin + rigorous margin
    float tmax = fmaxf(dmin[0], dmin[1]);
    for (int d = 32; d > 0; d >>= 1) tmax = fmaxf(tmax, __shfl_xor(tmax, d));
    if (lane == 0) wmax[w] = tmax;
    __syncthreads();
    float dmaxB = fmaxf(fmaxf(wmax[0], wmax[1]), fmaxf(wmax[2], wmax[3])) + 1.0f;

    // ---- keep-mask: remaining ks whose y lower bound could still win
    {
        bool keep = false;
        if (tid < KSEG) {
            int k = tid;
            bool instat = (k >= kA0 && k < kA1);
            float cyf = c8[k * 8 + 0];
            float t0 = (float)y0t * ratio - cyf;     // cy below tile range
            float t1 = cyf - (float)y1t * ratio;     // cy above tile range
            float t = fmaxf(fmaxf(t0, t1), 0.0f);
            keep = (!instat) && (t * t <= dmaxB);    // lb <= dmax+margin
        }
        unsigned long long bm = __ballot(keep);
        if (lane == 0 && w < 2) kmask[w] = bm;       // wave0: k0..63, wave1: k64..99
    }
    __syncthreads();

    // ---- phase B: surviving clusters (ascending k within each word)
    {
        unsigned long long m0 = kmask[0], m1 = kmask[1];
        while (m0) { int k = __builtin_ctzll(m0); m0 &= m0 - 1; EVALK(k); }
        while (m1) { int k = 64 + __builtin_ctzll(m1); m1 &= m1 - 1; EVALK(k); }
    }
#undef EVALK

    if (mode == 1) {
#pragma unroll
        for (int p = 0; p < 2; ++p) {
            int n = n0 + p * 256;
            outLab[(size_t)b * HWPIX + n] = (float)kb[p];
            float* om = outMean + ((size_t)b * HWPIX + n) * 3;
            om[0] = c8[kb[p] * 8 + 2];
            om[1] = c8[kb[p] * 8 + 3];
            om[2] = c8[kb[p] * 8 + 4];
        }
        return;
    }

    // ---- tile-local stable counting sort (order: p, wave, lane == ascending n)
    // Leader-ballot rank over DISTINCT labels present in the wave.
    unsigned long long lmask_lt = (lane == 0) ? 0ull : (~0ull >> (64 - lane));
    int rank_w[2], cnt_w[2];
#pragma unroll
    for (int p = 0; p < 2; ++p) {
        unsigned long long todo = __ballot(1);       // all active lanes
        while (todo) {
            int leader = __builtin_ctzll(todo);
            int lval = __shfl(kb[p], leader);
            unsigned long long mset = __ballot(kb[p] == lval);
            if (kb[p] == lval) {
                cnt_w[p] = (int)__popcll(mset);
                rank_w[p] = (int)__popcll(mset & lmask_lt);
            }
            todo &= ~mset;
        }
    }
#pragma unroll
    for (int p = 0; p < 2; ++p)
        if (rank_w[p] == 0) whist[(p * 4 + w) * KSEG + kb[p]] = cnt_w[p];
    __syncthreads();
    if (tid < KSEG) {
        int s = 0;
#pragma unroll
        for (int g = 0; g < 8; ++g) s += whist[g * KSEG + tid];
        tilecnt[tid] = s;
    }
    __syncthreads();
    // exclusive scan of tilecnt[100] via two shfl-scan chunks + carry
    if (tid < 64) {
        int v = tilecnt[tid];
        int incl = v;
        for (int d = 1; d < 64; d <<= 1) {
            int t = __shfl_up(incl, d);
            if (lane >= d) incl += t;
        }
        loffs[tid] = incl - v;
        if (lane == 63) sum0s = incl;
    }
    __syncthreads();
    if (w == 1) {                                    // tid 64..127 -> k 64..99
        int i2 = tid;
        int v = (i2 < KSEG) ? tilecnt[i2] : 0;
        int incl = v;
        for (int d = 1; d < 64; d <<= 1) {
            int t = __shfl_up(incl, d);
            if (lane >= d) incl += t;
        }
        if (i2 < KSEG) loffs[i2] = sum0s + incl - v;
    }
    __syncthreads();
    if (tid < KSEG) {
        cntT[((size_t)b * KSEG + tid) * NTILE + tile] = tilecnt[tid];
        startT[((size_t)b * KSEG + tid) * NTILE + tile] = loffs[tid];
    }

    // sort into LDS: ONE int scatter per pixel (was 5 float scatters)
#pragma unroll
    for (int p = 0; p < 2; ++p) {
        int g = p * 4 + w;
        int r = rank_w[p];
        for (int g2 = 0; g2 < g; ++g2) r += whist[g2 * KSEG + kb[p]];
        int pos = loffs[kb[p]] + r;
        sortedIdx[pos] = n0 + p * 256;               // pixel index, ascending per seg
    }
    __syncthreads();

    // ONE coalesced flat copy LDS -> tileIdx (512 contiguous ints, was 2560 f32)
    int* tb = tileIdx + (size_t)(b * NTILE + tile) * TPX;
    for (int i = tid; i < TPX; i += 256) tb[i] = sortedIdx[i];
}

// One block per (batch,cluster). Chunked shfl-scan of the 98 descriptors ->
// dstL (+total sentinel). Output-indexed gather: thread j binary-searches dstL
// (7 steps), fetches pixel index n, RE-DERIVES the 5 channels (y=n/224 exact
// int div; yf=(float)y*ratio identical expression to assign; r,g,b from img)
// into ubuf. Then 5 lanes run the EXACT ascending serial chains via pipelined
// float4 LDS reads (x,y,z,w index order).
__global__ void k_update(const float* __restrict__ img, const int* __restrict__ tileIdx,
                         const int* __restrict__ cntT, const int* __restrict__ startT,
                         float* __restrict__ centers) {
#pragma clang fp contract(off)
    __shared__ int srcL[NTILE];
    __shared__ int dstL[NTILE + 1];
    __shared__ float ubuf[5][UPITCH];
    int k = blockIdx.x, b = blockIdx.y, tid = threadIdx.x;
    int lane = tid & 63;
    float ratio = get_ratio();

    if (tid < 64) {
        int carry = 0;
        for (int c0 = 0; c0 < NTILE; c0 += 64) {
            int idx = c0 + lane;
            int c = (idx < NTILE) ? cntT[((size_t)b * KSEG + k) * NTILE + idx] : 0;
            int s = (idx < NTILE) ? startT[((size_t)b * KSEG + k) * NTILE + idx] : 0;
            int incl = c;
            for (int d = 1; d < 64; d <<= 1) {   // Hillis-Steele inclusive scan
                int t = __shfl_up(incl, d);
                if (lane >= d) incl += t;
            }
            if (idx < NTILE) { srcL[idx] = s; dstL[idx] = carry + incl - c; }
            carry += __shfl(incl, 63);
        }
        if (lane == 0) dstL[NTILE] = carry;
    }
    __syncthreads();
    int total = dstL[NTILE];

    float acc = 0.f;
    for (int c0 = 0; c0 < total; c0 += UCH) {
        int m = min(UCH, total - c0);
        for (int jj = tid; jj < m; jj += 256) {
            int j = c0 + jj;
            int lo = 0, hi = NTILE;          // dstL[0]=0 <= j < dstL[NTILE]
            while (hi - lo > 1) {            // 7 steps
                int mid = (lo + hi) >> 1;
                if (dstL[mid] <= j) lo = mid; else hi = mid;
            }
            int src = srcL[lo] + (j - dstL[lo]);
            int n = tileIdx[(size_t)(b * NTILE + lo) * TPX + src];
            int y = n / WW, x = n - y * WW;  // exact integer magic-div
            const float* pp = img + ((size_t)b * HWPIX + n) * 3;
            ubuf[0][jj] = (float)y * ratio;  // bit-identical to assign's yf
            ubuf[1][jj] = (float)x * ratio;
            ubuf[2][jj] = pp[0];
            ubuf[3][jj] = pp[1];
            ubuf[4][jj] = pp[2];
        }
        __syncthreads();
        if (tid < 5) {
            float a = acc;
            const float4* bp4 = reinterpret_cast<const float4*>(&ubuf[tid][0]);
            int nf4 = m >> 2;
#pragma unroll 4
            for (int i = 0; i < nf4; ++i) {  // loads pipeline; adds ascending
                float4 v = bp4[i];
                a = a + v.x;
                a = a + v.y;
                a = a + v.z;
                a = a + v.w;
            }
            for (int i = nf4 << 2; i < m; ++i) a = a + ubuf[tid][i];
            acc = a;
        }
        __syncthreads();
    }
    if (tid < 5 && total > 0) {              // where(counts>0, sums/counts, old)
        centers[(b * KSEG + k) * 5 + tid] = acc / (float)total;
    }
}

extern "C" void kernel_launch(void* const* d_in, const int* in_sizes, int n_in,
                              void* d_out, int out_size, void* d_ws, size_t ws_size,
                              hipStream_t stream) {
    const float* img = (const float*)d_in[0];
    float* outLab = (float*)d_out;                         // [8,224,224] labels as f32
    float* outMean = outLab + (size_t)BATCH * HWPIX;       // [8,224,224,3]

    char* ws = (char*)d_ws;
    float* centers = (float*)ws;  ws += (size_t)BATCH * KSEG * 5 * sizeof(float);
    int* tileIdx   = (int*)ws;    ws += (size_t)BATCH * NTILE * TPX * sizeof(int);
    int* cntT      = (int*)ws;    ws += (size_t)BATCH * KSEG * NTILE * sizeof(int);
    int* startT    = (int*)ws;    ws += (size_t)BATCH * KSEG * NTILE * sizeof(int);

    k_init<<<dim3(BATCH), 128, 0, stream>>>(img, centers);
    for (int it = 0; it < NITER; ++it) {
        k_assign<<<dim3(NTILE, BATCH), 256, 0, stream>>>(img, centers, tileIdx, cntT,
                                                         startT, outLab, outMean, 0);
        k_update<<<dim3(KSEG, BATCH), 256, 0, stream>>>(img, tileIdx, cntT, startT,
                                                        centers);
    }
    k_assign<<<dim3(NTILE, BATCH), 256, 0, stream>>>(img, centers, tileIdx, cntT,
                                                     startT, outLab, outMean, 1);
}

// Round 5
// 264.048 us; speedup vs baseline: 7.3450x; 1.0097x over previous
//
#include <hip/hip_runtime.h>
#include <math.h>

// SLIC superpixel segmentation — bit-faithful f32 reimplementation of the JAX ref
// (XLA CPU semantics). Numerics decisions, all aimed at exact label match:
//  - dot(feats, centers) replicates Eigen sgemm: sequential k=0..4 FMA chain.
//  - f_sq / c_sq: rounded squares, sequential adds, NO fma (fp contract off).
//  - d = (f_sq + c_sq) - 2*dot, three separately-rounded ops.
//  - argmin == first-min: (d < dmin) || (d == dmin && k < kbest) — order-free.
//  - segment_sum: EXACT ascending-pixel-index sequential adds per cluster.
// R24 (266.6us): tileBuf slimmed to sorted pixel-index list; update re-derives
// features from n (exact int div + identical float exprs + img loads).
// R25: three zero-numerics-risk grinds on the R24 budget (41 fill + ~28
// boundaries + ~197 work):
//  - EVALK LDS ops 3->2: c4,csq adjacent -> one float2 (ds_read_b64).
//  - k_init folded into mode-2 first assign (centers computed locally,
//    bit-identical exprs; tile-0 writes global init to cover total==0
//    keep-old case — update only ever WRITES centers). -1 launch.
//  - cntT/startT packed as int2 (one dwordx2 per descriptor each way).
// Same integers, same op order -> outputs bit-identical to R24.

#pragma clang fp contract(off)

#define BATCH 8
#define HH 224
#define WW 224
#define HWPIX (HH * WW)        // 50176
#define KSEG 100
#define TPX 512                // pixels per tile
#define NTILE 98               // 512-px tiles per batch (98*512 == 50176)
#define NITER 10
#define UCH 1024               // update output chunk
#define UPITCH (UCH + 4)       // row stride: 4112B = 257*16, 16B-aligned

__device__ __forceinline__ float get_ratio() {
    double S = sqrt((double)(HH * WW) / (double)KSEG);
    return (float)(10.0 / S);
}

// 2 pixels/thread: n = tile*512 + p*256 + tid. Ascending n == lex (p, w, lane).
// mode 2: first iteration — init centers computed locally (== old k_init),
//         tile-0 also writes them to global; then argmin + sort as mode 0.
// mode 0: argmin (pruned) + tile-local counting sort -> tileIdx + cntStart.
// mode 1: final outputs only.
__global__ void k_assign(const float* __restrict__ img, float* __restrict__ centers,
                         int* __restrict__ tileIdx, int2* __restrict__ cntStart,
                         float* __restrict__ outLab, float* __restrict__ outMean,
                         int mode) {
#pragma clang fp contract(off)
    __shared__ float c8[KSEG * 8];   // [c0..c4, csq, pad, pad]
    __shared__ int whist[8 * KSEG];  // group g = p*4 + w, lex order == pixel order
    __shared__ int tilecnt[KSEG];
    __shared__ int loffs[KSEG];
    __shared__ int sortedIdx[TPX];   // sorted pixel indices
    __shared__ float wmax[4];
    __shared__ unsigned long long kmask[2];
    __shared__ int sum0s;
    int b = blockIdx.y, tile = blockIdx.x, tid = threadIdx.x;
    int lane = tid & 63, w = tid >> 6;
    float ratio = get_ratio();

    if (mode == 2) {
        // init centers locally: pure function of img, identical exprs to the
        // old k_init -> bit-identical values in c8.
        if (tid < KSEG) {
            int k = tid;
            int i = k / 10, j = k % 10;
            int y = (int)floor(((i + 0.5) * (double)HH) / 10.0);
            int x = (int)floor(((j + 0.5) * (double)WW) / 10.0);
            int n = y * WW + x;
            const float* p = img + ((size_t)b * HWPIX + n) * 3;
            float c0 = (float)y * ratio, c1 = (float)x * ratio;
            c8[k * 8 + 0] = c0;
            c8[k * 8 + 1] = c1;
            c8[k * 8 + 2] = p[0];
            c8[k * 8 + 3] = p[1];
            c8[k * 8 + 4] = p[2];
            if (tile == 0) {     // global init: covers total==0 keep-old case
                float* c = centers + (b * KSEG + k) * 5;
                c[0] = c0; c[1] = c1; c[2] = p[0]; c[3] = p[1]; c[4] = p[2];
            }
        }
    } else {
        for (int i = tid; i < KSEG * 5; i += 256) {
            int k = i / 5, f = i - 5 * k;
            c8[k * 8 + f] = centers[(size_t)b * KSEG * 5 + i];
        }
    }
    if (mode != 1)
        for (int i = tid; i < 8 * KSEG; i += 256) whist[i] = 0;
    __syncthreads();
    if (tid < KSEG) {
        const float* ck = c8 + tid * 8;
        float s = ck[0] * ck[0];             // XLA fused mul+reduce: no fma, seq adds
        s = s + ck[1] * ck[1];
        s = s + ck[2] * ck[2];
        s = s + ck[3] * ck[3];
        s = s + ck[4] * ck[4];
        c8[tid * 8 + 5] = s;
    }
    __syncthreads();

    int n0 = tile * TPX + tid;
    float yf[2], xf[2], rr[2], gg[2], bb[2], fsq[2], dmin[2];
    int kb[2];
#pragma unroll
    for (int p = 0; p < 2; ++p) {
        int n = n0 + p * 256;
        int y = n / WW, x = n - y * WW;
        yf[p] = (float)y * ratio;
        xf[p] = (float)x * ratio;
        const float* pp = img + ((size_t)b * HWPIX + n) * 3;
        rr[p] = pp[0]; gg[p] = pp[1]; bb[p] = pp[2];
        float s = yf[p] * yf[p];             // no fma, seq adds (XLA reduce)
        s = s + xf[p] * xf[p];
        s = s + rr[p] * rr[p];
        s = s + gg[p] * gg[p];
        s = s + bb[p] * bb[p];
        fsq[p] = s;
        dmin[p] = INFINITY;
        kb[p] = 0;
    }

    // evaluate one cluster exactly (reference op order); order-free first-min rule
    // c0..c3 as float4 (b128), c4+csq as float2 (b64): 2 LDS ops, was 3.
#define EVALK(kk)                                                              \
    {                                                                          \
        int k_ = (kk);                                                         \
        float4 v0 = *reinterpret_cast<const float4*>(&c8[k_ * 8]);             \
        float2 v1 = *reinterpret_cast<const float2*>(&c8[k_ * 8 + 4]);         \
        _Pragma("unroll")                                                      \
        for (int p = 0; p < 2; ++p) {                                          \
            float dot = yf[p] * v0.x;                                          \
            dot = __fmaf_rn(xf[p], v0.y, dot);                                 \
            dot = __fmaf_rn(rr[p], v0.z, dot);                                 \
            dot = __fmaf_rn(gg[p], v0.w, dot);                                 \
            dot = __fmaf_rn(bb[p], v1.x, dot);                                 \
            float d = (fsq[p] + v1.y) - 2.0f * dot;                            \
            if (d < dmin[p] || (d == dmin[p] && k_ < kb[p])) {                 \
                dmin[p] = d; kb[p] = k_;                                       \
            }                                                                  \
        }                                                                      \
    }

    // ---- phase A: statically nearest cluster grid rows (ascending k)
    int y0t = (tile * TPX) / WW, y1t = (tile * TPX + TPX - 1) / WW;
    int rmid = ((y0t + y1t) / 2) * 10 / HH;          // nearest init grid row
    int rlo = (rmid > 0) ? rmid - 1 : 0;
    int rhi = (rmid < 9) ? rmid + 1 : 9;
    int kA0 = rlo * 10, kA1 = rhi * 10 + 10;         // 20..30 clusters
    for (int k = kA0; k < kA1; ++k) EVALK(k);

    // ---- block-max dmin + rigorous margin
    float tmax = fmaxf(dmin[0], dmin[1]);
    for (int d = 32; d > 0; d >>= 1) tmax = fmaxf(tmax, __shfl_xor(tmax, d));
    if (lane == 0) wmax[w] = tmax;
    __syncthreads();
    float dmaxB = fmaxf(fmaxf(wmax[0], wmax[1]), fmaxf(wmax[2], wmax[3])) + 1.0f;

    // ---- keep-mask: remaining ks whose y lower bound could still win
    {
        bool keep = false;
        if (tid < KSEG) {
            int k = tid;
            bool instat = (k >= kA0 && k < kA1);
            float cyf = c8[k * 8 + 0];
            float t0 = (float)y0t * ratio - cyf;     // cy below tile range
            float t1 = cyf - (float)y1t * ratio;     // cy above tile range
            float t = fmaxf(fmaxf(t0, t1), 0.0f);
            keep = (!instat) && (t * t <= dmaxB);    // lb <= dmax+margin
        }
        unsigned long long bm = __ballot(keep);
        if (lane == 0 && w < 2) kmask[w] = bm;       // wave0: k0..63, wave1: k64..99
    }
    __syncthreads();

    // ---- phase B: surviving clusters (ascending k within each word)
    {
        unsigned long long m0 = kmask[0], m1 = kmask[1];
        while (m0) { int k = __builtin_ctzll(m0); m0 &= m0 - 1; EVALK(k); }
        while (m1) { int k = 64 + __builtin_ctzll(m1); m1 &= m1 - 1; EVALK(k); }
    }
#undef EVALK

    if (mode == 1) {
#pragma unroll
        for (int p = 0; p < 2; ++p) {
            int n = n0 + p * 256;
            outLab[(size_t)b * HWPIX + n] = (float)kb[p];
            float* om = outMean + ((size_t)b * HWPIX + n) * 3;
            om[0] = c8[kb[p] * 8 + 2];
            om[1] = c8[kb[p] * 8 + 3];
            om[2] = c8[kb[p] * 8 + 4];
        }
        return;
    }

    // ---- tile-local stable counting sort (order: p, wave, lane == ascending n)
    // Leader-ballot rank over DISTINCT labels present in the wave.
    unsigned long long lmask_lt = (lane == 0) ? 0ull : (~0ull >> (64 - lane));
    int rank_w[2], cnt_w[2];
#pragma unroll
    for (int p = 0; p < 2; ++p) {
        unsigned long long todo = __ballot(1);       // all active lanes
        while (todo) {
            int leader = __builtin_ctzll(todo);
            int lval = __shfl(kb[p], leader);
            unsigned long long mset = __ballot(kb[p] == lval);
            if (kb[p] == lval) {
                cnt_w[p] = (int)__popcll(mset);
                rank_w[p] = (int)__popcll(mset & lmask_lt);
            }
            todo &= ~mset;
        }
    }
#pragma unroll
    for (int p = 0; p < 2; ++p)
        if (rank_w[p] == 0) whist[(p * 4 + w) * KSEG + kb[p]] = cnt_w[p];
    __syncthreads();
    if (tid < KSEG) {
        int s = 0;
#pragma unroll
        for (int g = 0; g < 8; ++g) s += whist[g * KSEG + tid];
        tilecnt[tid] = s;
    }
    __syncthreads();
    // exclusive scan of tilecnt[100] via two shfl-scan chunks + carry
    if (tid < 64) {
        int v = tilecnt[tid];
        int incl = v;
        for (int d = 1; d < 64; d <<= 1) {
            int t = __shfl_up(incl, d);
            if (lane >= d) incl += t;
        }
        loffs[tid] = incl - v;
        if (lane == 63) sum0s = incl;
    }
    __syncthreads();
    if (w == 1) {                                    // tid 64..127 -> k 64..99
        int i2 = tid;
        int v = (i2 < KSEG) ? tilecnt[i2] : 0;
        int incl = v;
        for (int d = 1; d < 64; d <<= 1) {
            int t = __shfl_up(incl, d);
            if (lane >= d) incl += t;
        }
        if (i2 < KSEG) loffs[i2] = sum0s + incl - v;
    }
    __syncthreads();
    if (tid < KSEG) {
        cntStart[((size_t)b * KSEG + tid) * NTILE + tile] =
            make_int2(tilecnt[tid], loffs[tid]);     // one dwordx2
    }

    // sort into LDS: ONE int scatter per pixel
#pragma unroll
    for (int p = 0; p < 2; ++p) {
        int g = p * 4 + w;
        int r = rank_w[p];
        for (int g2 = 0; g2 < g; ++g2) r += whist[g2 * KSEG + kb[p]];
        int pos = loffs[kb[p]] + r;
        sortedIdx[pos] = n0 + p * 256;               // pixel index, ascending per seg
    }
    __syncthreads();

    // ONE coalesced flat copy LDS -> tileIdx (512 contiguous ints)
    int* tb = tileIdx + (size_t)(b * NTILE + tile) * TPX;
    for (int i = tid; i < TPX; i += 256) tb[i] = sortedIdx[i];
}

// One block per (batch,cluster). Chunked shfl-scan of the 98 descriptors ->
// dstL (+total sentinel). Output-indexed gather: thread j binary-searches dstL
// (7 steps), fetches pixel index n, RE-DERIVES the 5 channels (y=n/224 exact
// int div; yf=(float)y*ratio identical expression to assign; r,g,b from img)
// into ubuf. Then 5 lanes run the EXACT ascending serial chains via pipelined
// float4 LDS reads (x,y,z,w index order).
__global__ void k_update(const float* __restrict__ img, const int* __restrict__ tileIdx,
                         const int2* __restrict__ cntStart, float* __restrict__ centers) {
#pragma clang fp contract(off)
    __shared__ int srcL[NTILE];
    __shared__ int dstL[NTILE + 1];
    __shared__ float ubuf[5][UPITCH];
    int k = blockIdx.x, b = blockIdx.y, tid = threadIdx.x;
    int lane = tid & 63;
    float ratio = get_ratio();

    if (tid < 64) {
        int carry = 0;
        for (int c0 = 0; c0 < NTILE; c0 += 64) {
            int idx = c0 + lane;
            int2 cs = (idx < NTILE)
                ? cntStart[((size_t)b * KSEG + k) * NTILE + idx] : make_int2(0, 0);
            int incl = cs.x;
            for (int d = 1; d < 64; d <<= 1) {   // Hillis-Steele inclusive scan
                int t = __shfl_up(incl, d);
                if (lane >= d) incl += t;
            }
            if (idx < NTILE) { srcL[idx] = cs.y; dstL[idx] = carry + incl - cs.x; }
            carry += __shfl(incl, 63);
        }
        if (lane == 0) dstL[NTILE] = carry;
    }
    __syncthreads();
    int total = dstL[NTILE];

    float acc = 0.f;
    for (int c0 = 0; c0 < total; c0 += UCH) {
        int m = min(UCH, total - c0);
        for (int jj = tid; jj < m; jj += 256) {
            int j = c0 + jj;
            int lo = 0, hi = NTILE;          // dstL[0]=0 <= j < dstL[NTILE]
            while (hi - lo > 1) {            // 7 steps
                int mid = (lo + hi) >> 1;
                if (dstL[mid] <= j) lo = mid; else hi = mid;
            }
            int src = srcL[lo] + (j - dstL[lo]);
            int n = tileIdx[(size_t)(b * NTILE + lo) * TPX + src];
            int y = n / WW, x = n - y * WW;  // exact integer magic-div
            const float* pp = img + ((size_t)b * HWPIX + n) * 3;
            ubuf[0][jj] = (float)y * ratio;  // bit-identical to assign's yf
            ubuf[1][jj] = (float)x * ratio;
            ubuf[2][jj] = pp[0];
            ubuf[3][jj] = pp[1];
            ubuf[4][jj] = pp[2];
        }
        __syncthreads();
        if (tid < 5) {
            float a = acc;
            const float4* bp4 = reinterpret_cast<const float4*>(&ubuf[tid][0]);
            int nf4 = m >> 2;
#pragma unroll 4
            for (int i = 0; i < nf4; ++i) {  // loads pipeline; adds ascending
                float4 v = bp4[i];
                a = a + v.x;
                a = a + v.y;
                a = a + v.z;
                a = a + v.w;
            }
            for (int i = nf4 << 2; i < m; ++i) a = a + ubuf[tid][i];
            acc = a;
        }
        __syncthreads();
    }
    if (tid < 5 && total > 0) {              // where(counts>0, sums/counts, old)
        centers[(b * KSEG + k) * 5 + tid] = acc / (float)total;
    }
}

extern "C" void kernel_launch(void* const* d_in, const int* in_sizes, int n_in,
                              void* d_out, int out_size, void* d_ws, size_t ws_size,
                              hipStream_t stream) {
    const float* img = (const float*)d_in[0];
    float* outLab = (float*)d_out;                         // [8,224,224] labels as f32
    float* outMean = outLab + (size_t)BATCH * HWPIX;       // [8,224,224,3]

    char* ws = (char*)d_ws;
    float* centers = (float*)ws;  ws += (size_t)BATCH * KSEG * 5 * sizeof(float);
    int* tileIdx   = (int*)ws;    ws += (size_t)BATCH * NTILE * TPX * sizeof(int);
    int2* cntStart = (int2*)ws;   ws += (size_t)BATCH * KSEG * NTILE * sizeof(int2);

    for (int it = 0; it < NITER; ++it) {
        k_assign<<<dim3(NTILE, BATCH), 256, 0, stream>>>(
            img, centers, tileIdx, cntStart, outLab, outMean, it == 0 ? 2 : 0);
        k_update<<<dim3(KSEG, BATCH), 256, 0, stream>>>(img, tileIdx, cntStart,
                                                        centers);
    }
    k_assign<<<dim3(NTILE, BATCH), 256, 0, stream>>>(
        img, centers, tileIdx, cntStart, outLab, outMean, 1);
}

// Round 6
// 260.067 us; speedup vs baseline: 7.4574x; 1.0153x over previous
//
#include <hip/hip_runtime.h>
#include <math.h>

// SLIC superpixel segmentation — bit-faithful f32 reimplementation of the JAX ref
// (XLA CPU semantics). Numerics decisions, all aimed at exact label match:
//  - dot(feats, centers) replicates Eigen sgemm: sequential k=0..4 FMA chain.
//  - f_sq / c_sq: rounded squares, sequential adds, NO fma (fp contract off).
//  - d = (f_sq + c_sq) - 2*dot, three separately-rounded ops.
//  - argmin == first-min: (d < dmin) || (d == dmin && k < kbest) — order-free.
//  - segment_sum: EXACT ascending-pixel-index sequential adds per cluster.
// R24 (266.6us): tileIdx slimmed to sorted pixel-index list; update re-derives
// features. R25 (264.0us): EVALK float2, k_init folded into mode-2 assign,
// int2 descriptors — mostly neutral -> assign is barrier/scan-bound, not
// LDS-issue-bound in the eval loop.
// R26: attack barrier count + sort/scan critical path (all integer-exact):
//  - per-WAVE keep-mask: shfl-max + 2 ballots replace LDS wmax/kmask round
//    trips (-2 barriers); wave max <= block max -> tighter, same margin logic.
//  - single-wave 100-elem scan with in-wave carry (-1 barrier, sum0s gone).
//  - whist pass leaves per-group EXCLUSIVE PREFIX in place -> pixel rank base
//    is 1 LDS read (was <=7-iter loop).
// 6 barriers (was 8). Same integers, same float op order -> bit-identical.

#pragma clang fp contract(off)

#define BATCH 8
#define HH 224
#define WW 224
#define HWPIX (HH * WW)        // 50176
#define KSEG 100
#define TPX 512                // pixels per tile
#define NTILE 98               // 512-px tiles per batch (98*512 == 50176)
#define NITER 10
#define UCH 1024               // update output chunk
#define UPITCH (UCH + 4)       // row stride: 4112B = 257*16, 16B-aligned

__device__ __forceinline__ float get_ratio() {
    double S = sqrt((double)(HH * WW) / (double)KSEG);
    return (float)(10.0 / S);
}

// 2 pixels/thread: n = tile*512 + p*256 + tid. Ascending n == lex (p, w, lane).
// mode 2: first iteration — init centers computed locally (== old k_init),
//         tile-0 also writes them to global; then argmin + sort as mode 0.
// mode 0: argmin (pruned) + tile-local counting sort -> tileIdx + cntStart.
// mode 1: final outputs only.
__global__ void k_assign(const float* __restrict__ img, float* __restrict__ centers,
                         int* __restrict__ tileIdx, int2* __restrict__ cntStart,
                         float* __restrict__ outLab, float* __restrict__ outMean,
                         int mode) {
#pragma clang fp contract(off)
    __shared__ float c8[KSEG * 8];   // [c0..c4, csq, pad, pad]
    __shared__ int whist[8 * KSEG];  // group g = p*4 + w; becomes excl. prefix
    __shared__ int tilecnt[KSEG];
    __shared__ int loffs[KSEG];
    __shared__ int sortedIdx[TPX];   // sorted pixel indices
    int b = blockIdx.y, tile = blockIdx.x, tid = threadIdx.x;
    int lane = tid & 63, w = tid >> 6;
    float ratio = get_ratio();

    if (mode == 2) {
        // init centers locally: pure function of img, identical exprs to the
        // old k_init -> bit-identical values in c8.
        if (tid < KSEG) {
            int k = tid;
            int i = k / 10, j = k % 10;
            int y = (int)floor(((i + 0.5) * (double)HH) / 10.0);
            int x = (int)floor(((j + 0.5) * (double)WW) / 10.0);
            int n = y * WW + x;
            const float* p = img + ((size_t)b * HWPIX + n) * 3;
            float c0 = (float)y * ratio, c1 = (float)x * ratio;
            c8[k * 8 + 0] = c0;
            c8[k * 8 + 1] = c1;
            c8[k * 8 + 2] = p[0];
            c8[k * 8 + 3] = p[1];
            c8[k * 8 + 4] = p[2];
            if (tile == 0) {     // global init: covers total==0 keep-old case
                float* c = centers + (b * KSEG + k) * 5;
                c[0] = c0; c[1] = c1; c[2] = p[0]; c[3] = p[1]; c[4] = p[2];
            }
        }
    } else {
        for (int i = tid; i < KSEG * 5; i += 256) {
            int k = i / 5, f = i - 5 * k;
            c8[k * 8 + f] = centers[(size_t)b * KSEG * 5 + i];
        }
    }
    if (mode != 1)
        for (int i = tid; i < 8 * KSEG; i += 256) whist[i] = 0;
    __syncthreads();                                 // (1)
    if (tid < KSEG) {
        const float* ck = c8 + tid * 8;
        float s = ck[0] * ck[0];             // XLA fused mul+reduce: no fma, seq adds
        s = s + ck[1] * ck[1];
        s = s + ck[2] * ck[2];
        s = s + ck[3] * ck[3];
        s = s + ck[4] * ck[4];
        c8[tid * 8 + 5] = s;
    }
    __syncthreads();                                 // (2)

    int n0 = tile * TPX + tid;
    float yf[2], xf[2], rr[2], gg[2], bb[2], fsq[2], dmin[2];
    int kb[2];
#pragma unroll
    for (int p = 0; p < 2; ++p) {
        int n = n0 + p * 256;
        int y = n / WW, x = n - y * WW;
        yf[p] = (float)y * ratio;
        xf[p] = (float)x * ratio;
        const float* pp = img + ((size_t)b * HWPIX + n) * 3;
        rr[p] = pp[0]; gg[p] = pp[1]; bb[p] = pp[2];
        float s = yf[p] * yf[p];             // no fma, seq adds (XLA reduce)
        s = s + xf[p] * xf[p];
        s = s + rr[p] * rr[p];
        s = s + gg[p] * gg[p];
        s = s + bb[p] * bb[p];
        fsq[p] = s;
        dmin[p] = INFINITY;
        kb[p] = 0;
    }

    // evaluate one cluster exactly (reference op order); order-free first-min rule
#define EVALK(kk)                                                              \
    {                                                                          \
        int k_ = (kk);                                                         \
        float4 v0 = *reinterpret_cast<const float4*>(&c8[k_ * 8]);             \
        float2 v1 = *reinterpret_cast<const float2*>(&c8[k_ * 8 + 4]);         \
        _Pragma("unroll")                                                      \
        for (int p = 0; p < 2; ++p) {                                          \
            float dot = yf[p] * v0.x;                                          \
            dot = __fmaf_rn(xf[p], v0.y, dot);                                 \
            dot = __fmaf_rn(rr[p], v0.z, dot);                                 \
            dot = __fmaf_rn(gg[p], v0.w, dot);                                 \
            dot = __fmaf_rn(bb[p], v1.x, dot);                                 \
            float d = (fsq[p] + v1.y) - 2.0f * dot;                            \
            if (d < dmin[p] || (d == dmin[p] && k_ < kb[p])) {                 \
                dmin[p] = d; kb[p] = k_;                                       \
            }                                                                  \
        }                                                                      \
    }

    // ---- phase A: statically nearest cluster grid rows (ascending k)
    int y0t = (tile * TPX) / WW, y1t = (tile * TPX + TPX - 1) / WW;
    int rmid = ((y0t + y1t) / 2) * 10 / HH;          // nearest init grid row
    int rlo = (rmid > 0) ? rmid - 1 : 0;
    int rhi = (rmid < 9) ? rmid + 1 : 9;
    int kA0 = rlo * 10, kA1 = rhi * 10 + 10;         // 20..30 clusters
    for (int k = kA0; k < kA1; ++k) EVALK(k);

    // ---- per-WAVE max dmin + rigorous margin (no LDS, no barriers)
    float tmax = fmaxf(dmin[0], dmin[1]);
    for (int d = 32; d > 0; d >>= 1) tmax = fmaxf(tmax, __shfl_xor(tmax, d));
    float dmaxW = tmax + 1.0f;

    // ---- per-wave keep-mask: remaining ks whose y lower bound could still win
    unsigned long long m0, m1;
    {
        int k1 = lane;                               // k 0..63
        bool instat1 = (k1 >= kA0 && k1 < kA1);
        float cyf1 = c8[k1 * 8 + 0];
        float t01 = (float)y0t * ratio - cyf1;       // cy below tile range
        float t11 = cyf1 - (float)y1t * ratio;       // cy above tile range
        float t1v = fmaxf(fmaxf(t01, t11), 0.0f);
        m0 = __ballot((!instat1) && (t1v * t1v <= dmaxW));
        int k2 = 64 + lane;                          // k 64..99 (lane<36)
        bool keep2 = false;
        if (k2 < KSEG) {
            bool instat2 = (k2 >= kA0 && k2 < kA1);
            float cyf2 = c8[k2 * 8 + 0];
            float t02 = (float)y0t * ratio - cyf2;
            float t12 = cyf2 - (float)y1t * ratio;
            float t2v = fmaxf(fmaxf(t02, t12), 0.0f);
            keep2 = (!instat2) && (t2v * t2v <= dmaxW);
        }
        m1 = __ballot(keep2);
    }

    // ---- phase B: surviving clusters (ascending k within each word)
    while (m0) { int k = __builtin_ctzll(m0); m0 &= m0 - 1; EVALK(k); }
    while (m1) { int k = 64 + __builtin_ctzll(m1); m1 &= m1 - 1; EVALK(k); }
#undef EVALK

    if (mode == 1) {
#pragma unroll
        for (int p = 0; p < 2; ++p) {
            int n = n0 + p * 256;
            outLab[(size_t)b * HWPIX + n] = (float)kb[p];
            float* om = outMean + ((size_t)b * HWPIX + n) * 3;
            om[0] = c8[kb[p] * 8 + 2];
            om[1] = c8[kb[p] * 8 + 3];
            om[2] = c8[kb[p] * 8 + 4];
        }
        return;
    }

    // ---- tile-local stable counting sort (order: p, wave, lane == ascending n)
    // Leader-ballot rank over DISTINCT labels present in the wave.
    unsigned long long lmask_lt = (lane == 0) ? 0ull : (~0ull >> (64 - lane));
    int rank_w[2], cnt_w[2];
#pragma unroll
    for (int p = 0; p < 2; ++p) {
        unsigned long long todo = __ballot(1);       // all active lanes
        while (todo) {
            int leader = __builtin_ctzll(todo);
            int lval = __shfl(kb[p], leader);
            unsigned long long mset = __ballot(kb[p] == lval);
            if (kb[p] == lval) {
                cnt_w[p] = (int)__popcll(mset);
                rank_w[p] = (int)__popcll(mset & lmask_lt);
            }
            todo &= ~mset;
        }
    }
#pragma unroll
    for (int p = 0; p < 2; ++p)
        if (rank_w[p] == 0) whist[(p * 4 + w) * KSEG + kb[p]] = cnt_w[p];
    __syncthreads();                                 // (3)
    if (tid < KSEG) {
        int s = 0;
#pragma unroll
        for (int g = 0; g < 8; ++g) {                // sum AND leave exclusive
            int t = whist[g * KSEG + tid];           // prefix in place
            whist[g * KSEG + tid] = s;
            s += t;
        }
        tilecnt[tid] = s;
    }
    __syncthreads();                                 // (4)
    // exclusive scan of tilecnt[100]: ONE wave, two chunks, in-wave carry
    if (tid < 64) {
        int v = tilecnt[lane];
        int incl = v;
        for (int d = 1; d < 64; d <<= 1) {
            int t = __shfl_up(incl, d);
            if (lane >= d) incl += t;
        }
        loffs[lane] = incl - v;
        int carry = __shfl(incl, 63);
        int i2 = 64 + lane;                          // k 64..99
        int v2 = (i2 < KSEG) ? tilecnt[i2] : 0;
        int incl2 = v2;
        for (int d = 1; d < 64; d <<= 1) {
            int t = __shfl_up(incl2, d);
            if (lane >= d) incl2 += t;
        }
        if (i2 < KSEG) loffs[i2] = carry + incl2 - v2;
    }
    __syncthreads();                                 // (5)
    if (tid < KSEG) {
        cntStart[((size_t)b * KSEG + tid) * NTILE + tile] =
            make_int2(tilecnt[tid], loffs[tid]);     // one dwordx2
    }

    // sort into LDS: ONE int scatter per pixel; rank base = 1 LDS read
#pragma unroll
    for (int p = 0; p < 2; ++p) {
        int g = p * 4 + w;
        int pos = loffs[kb[p]] + rank_w[p] + whist[g * KSEG + kb[p]];
        sortedIdx[pos] = n0 + p * 256;               // pixel index, ascending per seg
    }
    __syncthreads();                                 // (6)

    // ONE coalesced flat copy LDS -> tileIdx (512 contiguous ints)
    int* tb = tileIdx + (size_t)(b * NTILE + tile) * TPX;
    for (int i = tid; i < TPX; i += 256) tb[i] = sortedIdx[i];
}

// One block per (batch,cluster). Chunked shfl-scan of the 98 descriptors ->
// dstL (+total sentinel). Output-indexed gather: thread j binary-searches dstL
// (7 steps), fetches pixel index n, RE-DERIVES the 5 channels (y=n/224 exact
// int div; yf=(float)y*ratio identical expression to assign; r,g,b from img)
// into ubuf. Then 5 lanes run the EXACT ascending serial chains via pipelined
// float4 LDS reads (x,y,z,w index order).
__global__ void k_update(const float* __restrict__ img, const int* __restrict__ tileIdx,
                         const int2* __restrict__ cntStart, float* __restrict__ centers) {
#pragma clang fp contract(off)
    __shared__ int srcL[NTILE];
    __shared__ int dstL[NTILE + 1];
    __shared__ float ubuf[5][UPITCH];
    int k = blockIdx.x, b = blockIdx.y, tid = threadIdx.x;
    int lane = tid & 63;
    float ratio = get_ratio();

    if (tid < 64) {
        int carry = 0;
        for (int c0 = 0; c0 < NTILE; c0 += 64) {
            int idx = c0 + lane;
            int2 cs = (idx < NTILE)
                ? cntStart[((size_t)b * KSEG + k) * NTILE + idx] : make_int2(0, 0);
            int incl = cs.x;
            for (int d = 1; d < 64; d <<= 1) {   // Hillis-Steele inclusive scan
                int t = __shfl_up(incl, d);
                if (lane >= d) incl += t;
            }
            if (idx < NTILE) { srcL[idx] = cs.y; dstL[idx] = carry + incl - cs.x; }
            carry += __shfl(incl, 63);
        }
        if (lane == 0) dstL[NTILE] = carry;
    }
    __syncthreads();
    int total = dstL[NTILE];

    float acc = 0.f;
    for (int c0 = 0; c0 < total; c0 += UCH) {
        int m = min(UCH, total - c0);
        for (int jj = tid; jj < m; jj += 256) {
            int j = c0 + jj;
            int lo = 0, hi = NTILE;          // dstL[0]=0 <= j < dstL[NTILE]
            while (hi - lo > 1) {            // 7 steps
                int mid = (lo + hi) >> 1;
                if (dstL[mid] <= j) lo = mid; else hi = mid;
            }
            int src = srcL[lo] + (j - dstL[lo]);
            int n = tileIdx[(size_t)(b * NTILE + lo) * TPX + src];
            int y = n / WW, x = n - y * WW;  // exact integer magic-div
            const float* pp = img + ((size_t)b * HWPIX + n) * 3;
            ubuf[0][jj] = (float)y * ratio;  // bit-identical to assign's yf
            ubuf[1][jj] = (float)x * ratio;
            ubuf[2][jj] = pp[0];
            ubuf[3][jj] = pp[1];
            ubuf[4][jj] = pp[2];
        }
        __syncthreads();
        if (tid < 5) {
            float a = acc;
            const float4* bp4 = reinterpret_cast<const float4*>(&ubuf[tid][0]);
            int nf4 = m >> 2;
#pragma unroll 4
            for (int i = 0; i < nf4; ++i) {  // loads pipeline; adds ascending
                float4 v = bp4[i];
                a = a + v.x;
                a = a + v.y;
                a = a + v.z;
                a = a + v.w;
            }
            for (int i = nf4 << 2; i < m; ++i) a = a + ubuf[tid][i];
            acc = a;
        }
        __syncthreads();
    }
    if (tid < 5 && total > 0) {              // where(counts>0, sums/counts, old)
        centers[(b * KSEG + k) * 5 + tid] = acc / (float)total;
    }
}

extern "C" void kernel_launch(void* const* d_in, const int* in_sizes, int n_in,
                              void* d_out, int out_size, void* d_ws, size_t ws_size,
                              hipStream_t stream) {
    const float* img = (const float*)d_in[0];
    float* outLab = (float*)d_out;                         // [8,224,224] labels as f32
    float* outMean = outLab + (size_t)BATCH * HWPIX;       // [8,224,224,3]

    char* ws = (char*)d_ws;
    float* centers = (float*)ws;  ws += (size_t)BATCH * KSEG * 5 * sizeof(float);
    int* tileIdx   = (int*)ws;    ws += (size_t)BATCH * NTILE * TPX * sizeof(int);
    int2* cntStart = (int2*)ws;   ws += (size_t)BATCH * KSEG * NTILE * sizeof(int2);

    for (int it = 0; it < NITER; ++it) {
        k_assign<<<dim3(NTILE, BATCH), 256, 0, stream>>>(
            img, centers, tileIdx, cntStart, outLab, outMean, it == 0 ? 2 : 0);
        k_update<<<dim3(KSEG, BATCH), 256, 0, stream>>>(img, tileIdx, cntStart,
                                                        centers);
    }
    k_assign<<<dim3(NTILE, BATCH), 256, 0, stream>>>(
        img, centers, tileIdx, cntStart, outLab, outMean, 1);
}

// Round 7
// 257.760 us; speedup vs baseline: 7.5241x; 1.0090x over previous
//
#include <hip/hip_runtime.h>
#include <math.h>

// SLIC superpixel segmentation — bit-faithful f32 reimplementation of the JAX ref
// (XLA CPU semantics). Numerics decisions, all aimed at exact label match:
//  - dot(feats, centers) replicates Eigen sgemm: sequential k=0..4 FMA chain.
//  - f_sq / c_sq: rounded squares, sequential adds, NO fma (fp contract off).
//  - d = (f_sq + c_sq) - 2*dot, three separately-rounded ops.
//  - argmin == first-min: (d < dmin) || (d == dmin && k < kbest) — order-free.
//  - segment_sum: EXACT ascending-pixel-index sequential adds per cluster.
// R26 (260.1us): per-wave keep-mask, single-wave scan, whist excl-prefix —
// barriers are only ~0.15us each; the real cost is latency CHAINS.
// R27: attack the two longest chains (all integer-exact):
//  - update: per-element 7-step LDS bsearch (840cy dependent) replaced by a
//    parallel per-TILE fill of an LDS nmap (thread t writes its tile's
//    intersection with the chunk; tileIdx reads are independent/pipelined).
//    Gather chain: 1.9Kcy -> ~520cy.
//  - assign: centers loaded K-MAJOR into registers (thread k: 5 floats +
//    csq seq-adds + one 6-word LDS write) — kills one barrier + one stage;
//    sorted indices scattered DIRECTLY to global tileIdx (same-label lanes
//    hit consecutive addresses -> L2 coalesces; no LDS stage + copy).
//  Assign: 4 barriers (was 6). Same integers, same float op order ->
//  bit-identical outputs.

#pragma clang fp contract(off)

#define BATCH 8
#define HH 224
#define WW 224
#define HWPIX (HH * WW)        // 50176
#define KSEG 100
#define TPX 512                // pixels per tile
#define NTILE 98               // 512-px tiles per batch (98*512 == 50176)
#define NITER 10
#define UCH 1024               // update output chunk
#define UPITCH (UCH + 4)       // row stride: 4112B = 257*16, 16B-aligned

__device__ __forceinline__ float get_ratio() {
    double S = sqrt((double)(HH * WW) / (double)KSEG);
    return (float)(10.0 / S);
}

// 2 pixels/thread: n = tile*512 + p*256 + tid. Ascending n == lex (p, w, lane).
// mode 2: first iteration — init centers computed locally (== old k_init),
//         tile-0 also writes them to global; then argmin + sort as mode 0.
// mode 0: argmin (pruned) + tile-local counting sort -> tileIdx + cntStart.
// mode 1: final outputs only.
__global__ void k_assign(const float* __restrict__ img, float* __restrict__ centers,
                         int* __restrict__ tileIdx, int2* __restrict__ cntStart,
                         float* __restrict__ outLab, float* __restrict__ outMean,
                         int mode) {
#pragma clang fp contract(off)
    __shared__ float c8[KSEG * 8];   // [c0..c4, csq, pad, pad]
    __shared__ int whist[8 * KSEG];  // group g = p*4 + w; becomes excl. prefix
    __shared__ int tilecnt[KSEG];
    __shared__ int loffs[KSEG];
    int b = blockIdx.y, tile = blockIdx.x, tid = threadIdx.x;
    int lane = tid & 63, w = tid >> 6;
    float ratio = get_ratio();

    // ---- phase 0: centers k-major into registers, csq seq-adds, ONE LDS write
    if (mode == 2) {
        // init centers locally: pure function of img, identical exprs to the
        // old k_init -> bit-identical values.
        if (tid < KSEG) {
            int k = tid;
            int i = k / 10, j = k % 10;
            int y = (int)floor(((i + 0.5) * (double)HH) / 10.0);
            int x = (int)floor(((j + 0.5) * (double)WW) / 10.0);
            int n = y * WW + x;
            const float* p = img + ((size_t)b * HWPIX + n) * 3;
            float c0 = (float)y * ratio, c1 = (float)x * ratio;
            float c2 = p[0], c3 = p[1], c4 = p[2];
            float s = c0 * c0;               // XLA fused mul+reduce: no fma
            s = s + c1 * c1;
            s = s + c2 * c2;
            s = s + c3 * c3;
            s = s + c4 * c4;
            float* cw = c8 + k * 8;
            cw[0] = c0; cw[1] = c1; cw[2] = c2; cw[3] = c3; cw[4] = c4; cw[5] = s;
            if (tile == 0) {     // global init: covers total==0 keep-old case
                float* c = centers + (b * KSEG + k) * 5;
                c[0] = c0; c[1] = c1; c[2] = c2; c[3] = c3; c[4] = c4;
            }
        }
    } else {
        if (tid < KSEG) {
            const float* cg = centers + ((size_t)b * KSEG + tid) * 5;
            float c0 = cg[0], c1 = cg[1], c2 = cg[2], c3 = cg[3], c4 = cg[4];
            float s = c0 * c0;               // same seq-add order as ever
            s = s + c1 * c1;
            s = s + c2 * c2;
            s = s + c3 * c3;
            s = s + c4 * c4;
            float* cw = c8 + tid * 8;
            cw[0] = c0; cw[1] = c1; cw[2] = c2; cw[3] = c3; cw[4] = c4; cw[5] = s;
        }
    }
    if (mode != 1)
        for (int i = tid; i < 8 * KSEG; i += 256) whist[i] = 0;

    // ---- pixel features (registers only; overlaps the loads above)
    int n0 = tile * TPX + tid;
    float yf[2], xf[2], rr[2], gg[2], bb[2], fsq[2], dmin[2];
    int kb[2];
#pragma unroll
    for (int p = 0; p < 2; ++p) {
        int n = n0 + p * 256;
        int y = n / WW, x = n - y * WW;
        yf[p] = (float)y * ratio;
        xf[p] = (float)x * ratio;
        const float* pp = img + ((size_t)b * HWPIX + n) * 3;
        rr[p] = pp[0]; gg[p] = pp[1]; bb[p] = pp[2];
        float s = yf[p] * yf[p];             // no fma, seq adds (XLA reduce)
        s = s + xf[p] * xf[p];
        s = s + rr[p] * rr[p];
        s = s + gg[p] * gg[p];
        s = s + bb[p] * bb[p];
        fsq[p] = s;
        dmin[p] = INFINITY;
        kb[p] = 0;
    }
    __syncthreads();                                 // (A) c8 + whist ready

    // evaluate one cluster exactly (reference op order); order-free first-min rule
#define EVALK(kk)                                                              \
    {                                                                          \
        int k_ = (kk);                                                         \
        float4 v0 = *reinterpret_cast<const float4*>(&c8[k_ * 8]);             \
        float2 v1 = *reinterpret_cast<const float2*>(&c8[k_ * 8 + 4]);         \
        _Pragma("unroll")                                                      \
        for (int p = 0; p < 2; ++p) {                                          \
            float dot = yf[p] * v0.x;                                          \
            dot = __fmaf_rn(xf[p], v0.y, dot);                                 \
            dot = __fmaf_rn(rr[p], v0.z, dot);                                 \
            dot = __fmaf_rn(gg[p], v0.w, dot);                                 \
            dot = __fmaf_rn(bb[p], v1.x, dot);                                 \
            float d = (fsq[p] + v1.y) - 2.0f * dot;                            \
            if (d < dmin[p] || (d == dmin[p] && k_ < kb[p])) {                 \
                dmin[p] = d; kb[p] = k_;                                       \
            }                                                                  \
        }                                                                      \
    }

    // ---- phase A: statically nearest cluster grid rows (ascending k)
    int y0t = (tile * TPX) / WW, y1t = (tile * TPX + TPX - 1) / WW;
    int rmid = ((y0t + y1t) / 2) * 10 / HH;          // nearest init grid row
    int rlo = (rmid > 0) ? rmid - 1 : 0;
    int rhi = (rmid < 9) ? rmid + 1 : 9;
    int kA0 = rlo * 10, kA1 = rhi * 10 + 10;         // 20..30 clusters
    for (int k = kA0; k < kA1; ++k) EVALK(k);

    // ---- per-WAVE max dmin + rigorous margin (no LDS, no barriers)
    float tmax = fmaxf(dmin[0], dmin[1]);
    for (int d = 32; d > 0; d >>= 1) tmax = fmaxf(tmax, __shfl_xor(tmax, d));
    float dmaxW = tmax + 1.0f;

    // ---- per-wave keep-mask: remaining ks whose y lower bound could still win
    unsigned long long m0, m1;
    {
        int k1 = lane;                               // k 0..63
        bool instat1 = (k1 >= kA0 && k1 < kA1);
        float cyf1 = c8[k1 * 8 + 0];
        float t01 = (float)y0t * ratio - cyf1;       // cy below tile range
        float t11 = cyf1 - (float)y1t * ratio;       // cy above tile range
        float t1v = fmaxf(fmaxf(t01, t11), 0.0f);
        m0 = __ballot((!instat1) && (t1v * t1v <= dmaxW));
        int k2 = 64 + lane;                          // k 64..99 (lane<36)
        bool keep2 = false;
        if (k2 < KSEG) {
            bool instat2 = (k2 >= kA0 && k2 < kA1);
            float cyf2 = c8[k2 * 8 + 0];
            float t02 = (float)y0t * ratio - cyf2;
            float t12 = cyf2 - (float)y1t * ratio;
            float t2v = fmaxf(fmaxf(t02, t12), 0.0f);
            keep2 = (!instat2) && (t2v * t2v <= dmaxW);
        }
        m1 = __ballot(keep2);
    }

    // ---- phase B: surviving clusters (ascending k within each word)
    while (m0) { int k = __builtin_ctzll(m0); m0 &= m0 - 1; EVALK(k); }
    while (m1) { int k = 64 + __builtin_ctzll(m1); m1 &= m1 - 1; EVALK(k); }
#undef EVALK

    if (mode == 1) {
#pragma unroll
        for (int p = 0; p < 2; ++p) {
            int n = n0 + p * 256;
            outLab[(size_t)b * HWPIX + n] = (float)kb[p];
            float* om = outMean + ((size_t)b * HWPIX + n) * 3;
            om[0] = c8[kb[p] * 8 + 2];
            om[1] = c8[kb[p] * 8 + 3];
            om[2] = c8[kb[p] * 8 + 4];
        }
        return;
    }

    // ---- tile-local stable counting sort (order: p, wave, lane == ascending n)
    // Leader-ballot rank over DISTINCT labels present in the wave.
    unsigned long long lmask_lt = (lane == 0) ? 0ull : (~0ull >> (64 - lane));
    int rank_w[2], cnt_w[2];
#pragma unroll
    for (int p = 0; p < 2; ++p) {
        unsigned long long todo = __ballot(1);       // all active lanes
        while (todo) {
            int leader = __builtin_ctzll(todo);
            int lval = __shfl(kb[p], leader);
            unsigned long long mset = __ballot(kb[p] == lval);
            if (kb[p] == lval) {
                cnt_w[p] = (int)__popcll(mset);
                rank_w[p] = (int)__popcll(mset & lmask_lt);
            }
            todo &= ~mset;
        }
    }
#pragma unroll
    for (int p = 0; p < 2; ++p)
        if (rank_w[p] == 0) whist[(p * 4 + w) * KSEG + kb[p]] = cnt_w[p];
    __syncthreads();                                 // (B)
    if (tid < KSEG) {
        int s = 0;
#pragma unroll
        for (int g = 0; g < 8; ++g) {                // sum AND leave exclusive
            int t = whist[g * KSEG + tid];           // prefix in place
            whist[g * KSEG + tid] = s;
            s += t;
        }
        tilecnt[tid] = s;
    }
    __syncthreads();                                 // (C)
    // exclusive scan of tilecnt[100]: ONE wave, two chunks, in-wave carry
    if (tid < 64) {
        int v = tilecnt[lane];
        int incl = v;
        for (int d = 1; d < 64; d <<= 1) {
            int t = __shfl_up(incl, d);
            if (lane >= d) incl += t;
        }
        loffs[lane] = incl - v;
        int carry = __shfl(incl, 63);
        int i2 = 64 + lane;                          // k 64..99
        int v2 = (i2 < KSEG) ? tilecnt[i2] : 0;
        int incl2 = v2;
        for (int d = 1; d < 64; d <<= 1) {
            int t = __shfl_up(incl2, d);
            if (lane >= d) incl2 += t;
        }
        if (i2 < KSEG) loffs[i2] = carry + incl2 - v2;
    }
    __syncthreads();                                 // (D)
    if (tid < KSEG) {
        cntStart[((size_t)b * KSEG + tid) * NTILE + tile] =
            make_int2(tilecnt[tid], loffs[tid]);     // one dwordx2
    }

    // ---- DIRECT global scatter of sorted pixel indices (same integers as the
    // old LDS-stage+copy; same-label lanes hit consecutive addresses)
    int* tb = tileIdx + (size_t)(b * NTILE + tile) * TPX;
#pragma unroll
    for (int p = 0; p < 2; ++p) {
        int g = p * 4 + w;
        int pos = loffs[kb[p]] + rank_w[p] + whist[g * KSEG + kb[p]];
        tb[pos] = n0 + p * 256;                      // pixel index, asc per seg
    }
}

// One block per (batch,cluster). Chunked shfl-scan of the 98 descriptors ->
// dstL (+total sentinel). Per chunk: parallel per-TILE fill of nmap (thread t
// streams its tile's intersection of the chunk from tileIdx — independent,
// pipelined loads), then all 256 threads gather: RE-DERIVE the 5 channels
// (y=n/224 exact int div; yf=(float)y*ratio identical expression to assign;
// r,g,b from img) into ubuf. Then 5 lanes run the EXACT ascending serial
// chains via pipelined float4 LDS reads (x,y,z,w index order).
__global__ void k_update(const float* __restrict__ img, const int* __restrict__ tileIdx,
                         const int2* __restrict__ cntStart, float* __restrict__ centers) {
#pragma clang fp contract(off)
    __shared__ int srcL[NTILE];
    __shared__ int dstL[NTILE + 1];
    __shared__ int nmap[UCH];
    __shared__ float ubuf[5][UPITCH];
    int k = blockIdx.x, b = blockIdx.y, tid = threadIdx.x;
    int lane = tid & 63;
    float ratio = get_ratio();

    if (tid < 64) {
        int carry = 0;
        for (int c0 = 0; c0 < NTILE; c0 += 64) {
            int idx = c0 + lane;
            int2 cs = (idx < NTILE)
                ? cntStart[((size_t)b * KSEG + k) * NTILE + idx] : make_int2(0, 0);
            int incl = cs.x;
            for (int d = 1; d < 64; d <<= 1) {   // Hillis-Steele inclusive scan
                int t = __shfl_up(incl, d);
                if (lane >= d) incl += t;
            }
            if (idx < NTILE) { srcL[idx] = cs.y; dstL[idx] = carry + incl - cs.x; }
            carry += __shfl(incl, 63);
        }
        if (lane == 0) dstL[NTILE] = carry;
    }
    __syncthreads();
    int total = dstL[NTILE];

    float acc = 0.f;
    for (int c0 = 0; c0 < total; c0 += UCH) {
        int m = min(UCH, total - c0);
        // ---- parallel fill: thread t streams its tile's slice of this chunk
        if (tid < NTILE) {
            int t = tid;
            int d0 = dstL[t], d1 = dstL[t + 1];
            int lo = d0 > c0 ? d0 : c0;
            int hi = d1 < c0 + m ? d1 : c0 + m;
            if (lo < hi) {
                const int* tip = tileIdx + (size_t)(b * NTILE + t) * TPX
                                 + (srcL[t] + (lo - d0));
                for (int i = lo; i < hi; ++i)
                    nmap[i - c0] = tip[i - lo];      // independent loads, pipeline
            }
        }
        __syncthreads();
        // ---- gather: short chain nmap(LDS) -> img
        for (int jj = tid; jj < m; jj += 256) {
            int n = nmap[jj];
            int y = n / WW, x = n - y * WW;  // exact integer magic-div
            const float* pp = img + ((size_t)b * HWPIX + n) * 3;
            ubuf[0][jj] = (float)y * ratio;  // bit-identical to assign's yf
            ubuf[1][jj] = (float)x * ratio;
            ubuf[2][jj] = pp[0];
            ubuf[3][jj] = pp[1];
            ubuf[4][jj] = pp[2];
        }
        __syncthreads();
        if (tid < 5) {
            float a = acc;
            const float4* bp4 = reinterpret_cast<const float4*>(&ubuf[tid][0]);
            int nf4 = m >> 2;
#pragma unroll 4
            for (int i = 0; i < nf4; ++i) {  // loads pipeline; adds ascending
                float4 v = bp4[i];
                a = a + v.x;
                a = a + v.y;
                a = a + v.z;
                a = a + v.w;
            }
            for (int i = nf4 << 2; i < m; ++i) a = a + ubuf[tid][i];
            acc = a;
        }
        __syncthreads();
    }
    if (tid < 5 && total > 0) {              // where(counts>0, sums/counts, old)
        centers[(b * KSEG + k) * 5 + tid] = acc / (float)total;
    }
}

extern "C" void kernel_launch(void* const* d_in, const int* in_sizes, int n_in,
                              void* d_out, int out_size, void* d_ws, size_t ws_size,
                              hipStream_t stream) {
    const float* img = (const float*)d_in[0];
    float* outLab = (float*)d_out;                         // [8,224,224] labels as f32
    float* outMean = outLab + (size_t)BATCH * HWPIX;       // [8,224,224,3]

    char* ws = (char*)d_ws;
    float* centers = (float*)ws;  ws += (size_t)BATCH * KSEG * 5 * sizeof(float);
    int* tileIdx   = (int*)ws;    ws += (size_t)BATCH * NTILE * TPX * sizeof(int);
    int2* cntStart = (int2*)ws;   ws += (size_t)BATCH * KSEG * NTILE * sizeof(int2);

    for (int it = 0; it < NITER; ++it) {
        k_assign<<<dim3(NTILE, BATCH), 256, 0, stream>>>(
            img, centers, tileIdx, cntStart, outLab, outMean, it == 0 ? 2 : 0);
        k_update<<<dim3(KSEG, BATCH), 256, 0, stream>>>(img, tileIdx, cntStart,
                                                        centers);
    }
    k_assign<<<dim3(NTILE, BATCH), 256, 0, stream>>>(
        img, centers, tileIdx, cntStart, outLab, outMean, 1);
}